// Round 2
// baseline (731.952 us; speedup 1.0000x reference)
//
#include <hip/hip_runtime.h>
#include <hip/hip_bf16.h>

#define B_ 4
#define L_ 2048
#define E_ 1024
#define H_ 16
#define D_ 64

typedef unsigned short u16;
typedef unsigned short u16x8 __attribute__((ext_vector_type(8)));
typedef short s16x8 __attribute__((ext_vector_type(8)));
typedef float f32x4 __attribute__((ext_vector_type(4)));

__device__ inline u16 f2bf(float f) {
  union { float f; unsigned u; } v; v.f = f;
  unsigned r = v.u + 0x7fffu + ((v.u >> 16) & 1u);
  return (u16)(r >> 16);
}
__device__ inline float bf2f(u16 h) {
  union { unsigned u; float f; } v; v.u = ((unsigned)h) << 16;
  return v.f;
}

// ---------------- dtype detect: are float inputs f32 (flag=1) or bf16 (flag=0)? ----------------
// True bf16 N(0,1) data: biased exponent <= ~0x81, zero hits. f32-as-u16: even elements are
// mantissa halves with ~uniform high byte -> ~25% of them have exponent >= 0xC0 (~500 hits / 4096).
__global__ __launch_bounds__(256) void detect_k(const u16* __restrict__ q, int* __restrict__ flag) {
  int tid = threadIdx.x;
  int cnt = 0;
  for (int i = tid; i < 4096; i += 256) {
    unsigned e = (q[i] >> 7) & 0xFFu;
    if (e >= 0xC0u) cnt++;
  }
  __shared__ int s[256];
  s[tid] = cnt;
  __syncthreads();
  for (int off = 128; off; off >>= 1) {
    if (tid < off) s[tid] += s[tid + off];
    __syncthreads();
  }
  if (tid == 0) *flag = (s[0] >= 16) ? 1 : 0;
}

// ---------------- mask -> bitmask (1 wave per 64 mask ints) ----------------
__global__ __launch_bounds__(256) void mask_bits_k(const int* __restrict__ mask,
                                                   unsigned long long* __restrict__ bits,
                                                   int words) {
  int gw = (int)((blockIdx.x * 256 + threadIdx.x) >> 6);
  int lane = threadIdx.x & 63;
  if (gw >= words) return;
  int mv = mask[(size_t)gw * 64 + lane];
  unsigned long long bal = __ballot(mv != 0);
  if (lane == 0) bits[gw] = bal;
}

__device__ inline u16x8 load8_cvt(const void* base, size_t elem_off, int isf32) {
  if (isf32) {
    const float* p = (const float*)base + elem_off;
    f32x4 lo = *(const f32x4*)p;
    f32x4 hi = *(const f32x4*)(p + 4);
    u16x8 t;
#pragma unroll
    for (int j = 0; j < 4; ++j) { t[j] = f2bf(lo[j]); t[4 + j] = f2bf(hi[j]); }
    return t;
  } else {
    return *((const u16x8*)base + elem_off / 8);
  }
}

// ---------------- 128x128 NT GEMM: C[m,n] = sum_k A[m,k]*W[n,k] ----------------
// QKV=1: z selects (A,W,C); A,W dtype per flag; writes bf16 C as [B,H,L,D].
// QKV=0: A is bf16 (ws), W/bias dtype per flag, adds bias, writes [M,N] in flagged dtype.
template <int QKV>
__global__ __launch_bounds__(256) void gemm128(
    const void* __restrict__ A0, const void* __restrict__ A1, const void* __restrict__ A2,
    const void* __restrict__ W0, const void* __restrict__ W1, const void* __restrict__ W2,
    const void* __restrict__ bias,
    void* __restrict__ C0, u16* __restrict__ C1, u16* __restrict__ C2,
    int M, int N, int Kd, const int* __restrict__ flagp) {
  const void* A = A0; const void* W = W0; void* C = C0;
  if (QKV) {
    if (blockIdx.z == 1) { A = A1; W = W1; C = C1; }
    else if (blockIdx.z == 2) { A = A2; W = W2; C = C2; }
  }
  const int isf32 = *flagp;
  const int aF32 = QKV ? isf32 : 0;
  const int tid = threadIdx.x;
  const int wave = tid >> 6, lane = tid & 63;
  const int quad = lane >> 4, l16 = lane & 15;
  const int wm = wave >> 1, wn = wave & 1;
  const int m0 = blockIdx.y * 128, n0 = blockIdx.x * 128;

  __shared__ u16 As[128 * 32];
  __shared__ u16 Bs[128 * 32];

  f32x4 acc[4][4];
#pragma unroll
  for (int i = 0; i < 4; ++i)
#pragma unroll
    for (int j = 0; j < 4; ++j)
#pragma unroll
      for (int u = 0; u < 4; ++u) acc[i][j][u] = 0.f;

  const int row_s = tid >> 2;  // 0..63
  const int cb_s = tid & 3;    // 8-elem chunk 0..3

  for (int k0 = 0; k0 < Kd; k0 += 32) {
    __syncthreads();
#pragma unroll
    for (int rr = 0; rr < 2; ++rr) {
      int row = rr * 64 + row_s;
      int sw = (cb_s ^ ((row >> 1) & 3)) * 8;  // XOR swizzle: 2-way max on frag reads
      size_t off = (size_t)(m0 + row) * Kd + k0 + cb_s * 8;
      *(u16x8*)&As[row * 32 + sw] = load8_cvt(A, off, aF32);
      size_t offw = (size_t)(n0 + row) * Kd + k0 + cb_s * 8;
      *(u16x8*)&Bs[row * 32 + sw] = load8_cvt(W, offw, isf32);
    }
    __syncthreads();

    s16x8 af[4], bfv[4];
#pragma unroll
    for (int mt = 0; mt < 4; ++mt) {
      int row = wm * 64 + mt * 16 + l16;
      af[mt] = *(const s16x8*)&As[row * 32 + (quad ^ ((row >> 1) & 3)) * 8];
    }
#pragma unroll
    for (int nt = 0; nt < 4; ++nt) {
      int row = wn * 64 + nt * 16 + l16;
      bfv[nt] = *(const s16x8*)&Bs[row * 32 + (quad ^ ((row >> 1) & 3)) * 8];
    }
#pragma unroll
    for (int mt = 0; mt < 4; ++mt)
#pragma unroll
      for (int nt = 0; nt < 4; ++nt)
        acc[mt][nt] = __builtin_amdgcn_mfma_f32_16x16x32_bf16(af[mt], bfv[nt], acc[mt][nt], 0, 0, 0);
  }

#pragma unroll
  for (int mt = 0; mt < 4; ++mt) {
#pragma unroll
    for (int r = 0; r < 4; ++r) {
      int row = m0 + wm * 64 + mt * 16 + quad * 4 + r;
#pragma unroll
      for (int nt = 0; nt < 4; ++nt) {
        int col = n0 + wn * 64 + nt * 16 + l16;
        float v = acc[mt][nt][r];
        if (!QKV) {
          v += isf32 ? ((const float*)bias)[col] : bf2f(((const u16*)bias)[col]);
          if (isf32) ((float*)C)[(size_t)row * N + col] = v;
          else ((u16*)C)[(size_t)row * N + col] = f2bf(v);
        } else {
          int bb = row >> 11, l = row & (L_ - 1);
          int hh = col >> 6, d = col & 63;
          ((u16*)C)[(((size_t)bb * H_ + hh) * L_ + l) * D_ + d] = f2bf(v);
        }
      }
    }
  }
}

// ---------------- flash attention: 1 block = (b,h,64 q-rows), 4 waves x 16 rows ----------------
__global__ __launch_bounds__(256) void attn64(const u16* __restrict__ Qp, const u16* __restrict__ Kp,
                                              const u16* __restrict__ Vp,
                                              const unsigned long long* __restrict__ Mb,
                                              u16* __restrict__ AO) {
  const int qt = blockIdx.x, h = blockIdx.y, b = blockIdx.z;
  const int tid = threadIdx.x;
  const int wave = tid >> 6, lane = tid & 63;
  const int quad = lane >> 4, l16 = lane & 15;
  const size_t bh = ((size_t)b * H_ + h) * (size_t)(L_ * D_);
  const int q0 = qt * 64;

  __shared__ u16 Ks[64 * 72];     // [k][d], stride 72
  __shared__ u16 Vt[64 * 72];     // [d][k] transposed
  __shared__ u16 Ps[4][16 * 72];  // per-wave P scratch (C-layout -> A-layout round trip)

  s16x8 aq[2];
  {
    int qrow = q0 + wave * 16 + l16;
#pragma unroll
    for (int ks = 0; ks < 2; ++ks)
      aq[ks] = *(const s16x8*)&Qp[bh + (size_t)qrow * D_ + quad * 8 + 32 * ks];
  }

  f32x4 Oacc[4];
#pragma unroll
  for (int nt = 0; nt < 4; ++nt)
#pragma unroll
    for (int u = 0; u < 4; ++u) Oacc[nt][u] = 0.f;
  float m_i[4], l_i[4];
#pragma unroll
  for (int r = 0; r < 4; ++r) { m_i[r] = -3.0e38f; l_i[r] = 0.f; }

  const float invs = 0.03125f;  // 1/sqrt(E)=1/32, applied after masking (as reference)
  const float LOG2E = 1.44269504088896f;

  for (int kt = 0; kt < L_ / 64; ++kt) {
    const int k0 = kt * 64;
    __syncthreads();
#pragma unroll
    for (int rr = 0; rr < 2; ++rr) {
      int row = rr * 32 + (tid >> 3);
      int col = (tid & 7) * 8;
      *(u16x8*)&Ks[row * 72 + col] = *(const u16x8*)&Kp[bh + (size_t)(k0 + row) * D_ + col];
    }
    {
      int d0 = wave * 16;
#pragma unroll
      for (int half = 0; half < 2; ++half) {
        u16x8 tv = *(const u16x8*)&Vp[bh + (size_t)(k0 + lane) * D_ + d0 + half * 8];
#pragma unroll
        for (int j = 0; j < 8; ++j) Vt[(d0 + half * 8 + j) * 72 + lane] = tv[j];
      }
    }
    __syncthreads();

    f32x4 sacc[4];
#pragma unroll
    for (int nt = 0; nt < 4; ++nt) {
#pragma unroll
      for (int u = 0; u < 4; ++u) sacc[nt][u] = 0.f;
#pragma unroll
      for (int ks = 0; ks < 2; ++ks) {
        s16x8 bfr = *(const s16x8*)&Ks[(nt * 16 + l16) * 72 + quad * 8 + 32 * ks];
        sacc[nt] = __builtin_amdgcn_mfma_f32_16x16x32_bf16(aq[ks], bfr, sacc[nt], 0, 0, 0);
      }
    }

    float sv[4][4], alph[4];
#pragma unroll
    for (int r = 0; r < 4; ++r) {
      int row = q0 + wave * 16 + quad * 4 + r;
      unsigned long long mb = Mb[(size_t)(b * L_ + row) * (L_ / 64) + kt];
#pragma unroll
      for (int nt = 0; nt < 4; ++nt) {
        float s = sacc[nt][r] * invs;
        if (!((mb >> (nt * 16 + l16)) & 1ULL)) s = -3.125e18f;  // -1e20/32
        sv[nt][r] = s;
      }
      float mx = fmaxf(fmaxf(sv[0][r], sv[1][r]), fmaxf(sv[2][r], sv[3][r]));
      mx = fmaxf(mx, __shfl_xor(mx, 1));
      mx = fmaxf(mx, __shfl_xor(mx, 2));
      mx = fmaxf(mx, __shfl_xor(mx, 4));
      mx = fmaxf(mx, __shfl_xor(mx, 8));
      float newm = fmaxf(m_i[r], mx);
      float alpha = exp2f((m_i[r] - newm) * LOG2E);
      float rs = 0.f;
#pragma unroll
      for (int nt = 0; nt < 4; ++nt) {
        float p = exp2f((sv[nt][r] - newm) * LOG2E);
        rs += p;
        Ps[wave][(quad * 4 + r) * 72 + nt * 16 + l16] = f2bf(p);
      }
      rs += __shfl_xor(rs, 1);
      rs += __shfl_xor(rs, 2);
      rs += __shfl_xor(rs, 4);
      rs += __shfl_xor(rs, 8);
      l_i[r] = l_i[r] * alpha + rs;
      m_i[r] = newm;
      alph[r] = alpha;
    }
#pragma unroll
    for (int nt = 0; nt < 4; ++nt)
#pragma unroll
      for (int r = 0; r < 4; ++r) Oacc[nt][r] *= alph[r];

#pragma unroll
    for (int ks = 0; ks < 2; ++ks) {
      s16x8 pa = *(const s16x8*)&Ps[wave][l16 * 72 + quad * 8 + 32 * ks];
#pragma unroll
      for (int nt = 0; nt < 4; ++nt) {
        s16x8 vb = *(const s16x8*)&Vt[(nt * 16 + l16) * 72 + quad * 8 + 32 * ks];
        Oacc[nt] = __builtin_amdgcn_mfma_f32_16x16x32_bf16(pa, vb, Oacc[nt], 0, 0, 0);
      }
    }
  }

#pragma unroll
  for (int nt = 0; nt < 4; ++nt) {
#pragma unroll
    for (int r = 0; r < 4; ++r) {
      int row = q0 + wave * 16 + quad * 4 + r;
      int col = h * 64 + nt * 16 + l16;
      AO[((size_t)b * L_ + row) * E_ + col] = f2bf(Oacc[nt][r] / l_i[r]);
    }
  }
}

extern "C" void kernel_launch(void* const* d_in, const int* in_sizes, int n_in,
                              void* d_out, int out_size, void* d_ws, size_t ws_size,
                              hipStream_t stream) {
  const void* queries = d_in[0];
  const void* keys = d_in[1];
  const void* values = d_in[2];
  const int* mask = (const int*)d_in[3];
  const void* Wq = d_in[4];
  const void* Wk = d_in[5];
  const void* Wv = d_in[6];
  const void* Wo = d_in[7];
  const void* bo = d_in[8];

  char* ws = (char*)d_ws;
  const size_t SEG = (size_t)B_ * H_ * L_ * D_ * sizeof(u16);  // 16 MiB
  u16* Qp = (u16*)(ws);
  u16* Kp = (u16*)(ws + SEG);
  u16* Vp = (u16*)(ws + 2 * SEG);
  u16* AO = (u16*)(ws + 3 * SEG);
  int* flag = (int*)(ws + 4 * SEG);
  unsigned long long* Mb = (unsigned long long*)(ws + 4 * SEG + 256);

  // 0) dtype detection (f32 vs bf16 float tensors)
  hipLaunchKernelGGL(detect_k, dim3(1), dim3(256), 0, stream, (const u16*)queries, flag);

  // 1) mask -> bitmask
  int words = B_ * L_ * (L_ / 64);
  hipLaunchKernelGGL(mask_bits_k, dim3(words / 4), dim3(256), 0, stream, mask, Mb, words);

  // 2) QKV projections (fused via grid.z), outputs bf16 [B,H,L,D]
  dim3 g1(E_ / 128, (B_ * L_) / 128, 3);
  hipLaunchKernelGGL((gemm128<1>), g1, dim3(256), 0, stream,
                     queries, keys, values, Wq, Wk, Wv, (const void*)nullptr,
                     (void*)Qp, Kp, Vp, B_ * L_, E_, E_, flag);

  // 3) flash attention -> AO bf16 [B,L,E]
  hipLaunchKernelGGL(attn64, dim3(L_ / 64, H_, B_), dim3(256), 0, stream, Qp, Kp, Vp, Mb, AO);

  // 4) output projection + bias -> d_out [B,L,E] in flagged dtype
  dim3 g2(E_ / 128, (B_ * L_) / 128, 1);
  hipLaunchKernelGGL((gemm128<0>), g2, dim3(256), 0, stream,
                     (const void*)AO, (const void*)nullptr, (const void*)nullptr,
                     Wo, (const void*)nullptr, (const void*)nullptr, bo,
                     d_out, (u16*)nullptr, (u16*)nullptr, B_ * L_, E_, E_, flag);
}

// Round 3
// 486.321 us; speedup vs baseline: 1.5051x; 1.5051x over previous
//
#include <hip/hip_runtime.h>
#include <hip/hip_bf16.h>

#define B_ 4
#define L_ 2048
#define E_ 1024
#define H_ 16
#define D_ 64
#define KDIM 1024

typedef unsigned short u16;
typedef unsigned short u16x8 __attribute__((ext_vector_type(8)));
typedef short s16x8 __attribute__((ext_vector_type(8)));
typedef short s16x4 __attribute__((ext_vector_type(4)));
typedef float f32x4 __attribute__((ext_vector_type(4)));
typedef unsigned uint2v __attribute__((ext_vector_type(2)));

#define MFMA32(a, b, c) __builtin_amdgcn_mfma_f32_16x16x32_bf16(a, b, c, 0, 0, 0)

#if __has_builtin(__builtin_amdgcn_mfma_f32_16x16x16bf16_1k)
#define HAVE_M16 1
#define MFMA16(a, b, c) __builtin_amdgcn_mfma_f32_16x16x16bf16_1k(a, b, c, 0, 0, 0)
#else
#define HAVE_M16 0
#endif

__device__ inline u16 f2bf(float f) {
  union { float f; unsigned u; } v; v.f = f;
  unsigned r = v.u + 0x7fffu + ((v.u >> 16) & 1u);
  return (u16)(r >> 16);
}
__device__ inline float bf2f(u16 h) {
  union { unsigned u; float f; } v; v.u = ((unsigned)h) << 16;
  return v.f;
}
// pack 2 f32 -> 2 bf16 (round-half-up) in one v_perm after bit-rounding
__device__ inline unsigned permrne(float hi, float lo) {
  unsigned a = __float_as_uint(lo) + 0x8000u;
  unsigned b = __float_as_uint(hi) + 0x8000u;
  return __builtin_amdgcn_perm(b, a, 0x07060302u);
}
__device__ inline float bperm_f(int byteaddr, float v) {
  return __uint_as_float((unsigned)__builtin_amdgcn_ds_bpermute(byteaddr, (int)__float_as_uint(v)));
}

typedef __attribute__((address_space(1))) const unsigned as1_u32;
typedef __attribute__((address_space(3))) unsigned as3_u32;
__device__ inline void gl_lds16(const u16* g, u16* l) {
  __builtin_amdgcn_global_load_lds((as1_u32*)g, (as3_u32*)l, 16, 0, 0);
}

// ---------------- dtype detect: f32 (flag=1) vs bf16 (flag=0) float tensors ----------------
__global__ __launch_bounds__(256) void detect_k(const u16* __restrict__ q, int* __restrict__ flag) {
  int tid = threadIdx.x;
  int cnt = 0;
  for (int i = tid; i < 4096; i += 256) {
    unsigned e = (q[i] >> 7) & 0xFFu;
    if (e >= 0xC0u) cnt++;
  }
  __shared__ int s[256];
  s[tid] = cnt;
  __syncthreads();
  for (int off = 128; off; off >>= 1) {
    if (tid < off) s[tid] += s[tid + off];
    __syncthreads();
  }
  if (tid == 0) *flag = (s[0] >= 16) ? 1 : 0;
}

// ---------------- mask -> bitmask + all-ones flag ----------------
__global__ __launch_bounds__(256) void mask_bits_k(const int* __restrict__ mask,
                                                   unsigned long long* __restrict__ bits,
                                                   unsigned* __restrict__ gflag, int words) {
  int gw = (int)((blockIdx.x * 256 + threadIdx.x) >> 6);
  int lane = threadIdx.x & 63;
  if (gw >= words) return;
  int mv = mask[(size_t)gw * 64 + lane];
  unsigned long long bal = __ballot(mv != 0);
  if (lane == 0) {
    bits[gw] = bal;
    if (bal != ~0ULL) atomicAnd(gflag, 0u);
  }
}

// ---------------- conversion kernels ----------------
__global__ __launch_bounds__(256) void cvt_bf16_k(const void* __restrict__ src, u16* __restrict__ dst,
                                                  int n8, const int* __restrict__ flagp) {
  int i = blockIdx.x * 256 + threadIdx.x;
  if (i >= n8) return;
  if (*flagp) {
    const float* s = (const float*)src + (size_t)i * 8;
    f32x4 a = *(const f32x4*)s;
    f32x4 b = *(const f32x4*)(s + 4);
    u16x8 o;
#pragma unroll
    for (int j = 0; j < 4; ++j) { o[j] = f2bf(a[j]); o[4 + j] = f2bf(b[j]); }
    *((u16x8*)dst + i) = o;
  } else {
    *((u16x8*)dst + i) = *((const u16x8*)src + i);
  }
}
__global__ __launch_bounds__(256) void cvt_f32_k(const void* __restrict__ src, float* __restrict__ dst,
                                                 int n, const int* __restrict__ flagp) {
  int i = blockIdx.x * 256 + threadIdx.x;
  if (i >= n) return;
  dst[i] = (*flagp) ? ((const float*)src)[i] : bf2f(((const u16*)src)[i]);
}

// ================= m97-style GEMM core: 128x128 tile, BK=64, global_load_lds =================
// C[m,n] = sum_k A[m,k] * W[n,k], K = KDIM. LDS unpadded, source-side XOR chunk swizzle.
__device__ inline void gemm_core(const u16* __restrict__ A, const u16* __restrict__ W,
                                 int m0, int n0, u16* AsB, u16* BsB, f32x4 (&acc)[4][4]) {
  const int tid = threadIdx.x;
  const int wave = tid >> 6, lane = tid & 63;
  const int quad = lane >> 4, l16 = lane & 15;
  const int wm = wave >> 1, wn = wave & 1;
  const int lrow = lane >> 3;                 // 0..7
  const int lch = (lane & 7) ^ lrow;          // swizzled source chunk

#pragma unroll
  for (int i = 0; i < 4; ++i)
#pragma unroll
    for (int j = 0; j < 4; ++j)
#pragma unroll
      for (int u = 0; u < 4; ++u) acc[i][j][u] = 0.f;

  const u16* gA = A + (size_t)(m0 + wave * 32 + lrow) * KDIM + lch * 8;
  const u16* gB = W + (size_t)(n0 + wave * 32 + lrow) * KDIM + lch * 8;

  for (int k0 = 0; k0 < KDIM; k0 += 64) {
    __syncthreads();
#pragma unroll
    for (int i = 0; i < 4; ++i) {
      gl_lds16(gA + (size_t)i * 8 * KDIM + k0, &AsB[(wave * 32 + i * 8) * 64]);
      gl_lds16(gB + (size_t)i * 8 * KDIM + k0, &BsB[(wave * 32 + i * 8) * 64]);
    }
    __syncthreads();
#pragma unroll
    for (int ks = 0; ks < 2; ++ks) {
      s16x8 af[4], bf[4];
#pragma unroll
      for (int mt = 0; mt < 4; ++mt) {
        int row = wm * 64 + mt * 16 + l16;
        af[mt] = *(const s16x8*)&AsB[row * 64 + (((quad + 4 * ks) ^ (row & 7)) * 8)];
      }
#pragma unroll
      for (int nt = 0; nt < 4; ++nt) {
        int row = wn * 64 + nt * 16 + l16;
        bf[nt] = *(const s16x8*)&BsB[row * 64 + (((quad + 4 * ks) ^ (row & 7)) * 8)];
      }
#pragma unroll
      for (int mt = 0; mt < 4; ++mt)
#pragma unroll
        for (int nt = 0; nt < 4; ++nt)
          acc[mt][nt] = MFMA32(af[mt], bf[nt], acc[mt][nt]);
    }
  }
}

#define SCALE_Q 0.045084220f  /* (1/32) * log2(e) */
#define MASKC  -4.508422e18f  /* -1e20 * SCALE_Q */

// Q/K projections: z=0 -> Q (prescaled), z=1 -> K. Writes [B,H,L,D] bf16.
__global__ __launch_bounds__(256) void gemm_qk_k(
    const void* __restrict__ qor, const void* __restrict__ kor,
    const void* __restrict__ wqor, const void* __restrict__ wkor,
    const u16* __restrict__ qc, const u16* __restrict__ kc,
    const u16* __restrict__ wqc, const u16* __restrict__ wkc,
    u16* __restrict__ Qp, u16* __restrict__ Kp, const int* __restrict__ flagp) {
  const int isf32 = *flagp;
  const int z = blockIdx.z;
  const u16* A = z ? (isf32 ? kc : (const u16*)kor) : (isf32 ? qc : (const u16*)qor);
  const u16* W = z ? (isf32 ? wkc : (const u16*)wkor) : (isf32 ? wqc : (const u16*)wqor);
  u16* C = z ? Kp : Qp;
  const float scale = z ? 1.0f : SCALE_Q;
  __shared__ __align__(16) u16 As[128 * 64];
  __shared__ __align__(16) u16 Bs[128 * 64];
  f32x4 acc[4][4];
  const int m0 = blockIdx.y * 128, n0 = blockIdx.x * 128;
  gemm_core(A, W, m0, n0, As, Bs, acc);

  const int lane = threadIdx.x & 63, wave = threadIdx.x >> 6;
  const int quad = lane >> 4, l16 = lane & 15;
  const int wm = wave >> 1, wn = wave & 1;
#pragma unroll
  for (int mt = 0; mt < 4; ++mt)
#pragma unroll
    for (int r = 0; r < 4; ++r) {
      int row = m0 + wm * 64 + mt * 16 + quad * 4 + r;
      int bb = row >> 11, l = row & (L_ - 1);
#pragma unroll
      for (int nt = 0; nt < 4; ++nt) {
        int col = n0 + wn * 64 + nt * 16 + l16;
        int hh = col >> 6, d = col & 63;
        C[(((size_t)bb * H_ + hh) * L_ + l) * D_ + d] = f2bf(acc[mt][nt][r] * scale);
      }
    }
}

// V projection, transposed output: A = Wv (M=1024), W-op = values (N=8192) -> VpT [B,H,D,L]
__global__ __launch_bounds__(256) void gemm_vt_k(
    const void* __restrict__ vor, const void* __restrict__ wvor,
    const u16* __restrict__ vc, const u16* __restrict__ wvc,
    u16* __restrict__ VpT, const int* __restrict__ flagp) {
  const int isf32 = *flagp;
  const u16* A = isf32 ? wvc : (const u16*)wvor;
  const u16* W = isf32 ? vc : (const u16*)vor;
  __shared__ __align__(16) u16 As[128 * 64];
  __shared__ __align__(16) u16 Bs[128 * 64];
  f32x4 acc[4][4];
  const int m0 = blockIdx.y * 128, n0 = blockIdx.x * 128;
  gemm_core(A, W, m0, n0, As, Bs, acc);

  const int lane = threadIdx.x & 63, wave = threadIdx.x >> 6;
  const int quad = lane >> 4, l16 = lane & 15;
  const int wm = wave >> 1, wn = wave & 1;
#pragma unroll
  for (int mt = 0; mt < 4; ++mt)
#pragma unroll
    for (int r = 0; r < 4; ++r) {
      int o = m0 + wm * 64 + mt * 16 + quad * 4 + r;  // weight-out dim
      int hh = o >> 6, d = o & 63;
#pragma unroll
      for (int nt = 0; nt < 4; ++nt) {
        int t = n0 + wn * 64 + nt * 16 + l16;  // token
        int bb = t >> 11, l = t & (L_ - 1);
        VpT[(((size_t)bb * H_ + hh) * D_ + d) * L_ + l] = f2bf(acc[mt][nt][r]);
      }
    }
}

// Output projection + bias; writes d_out in flagged dtype
__global__ __launch_bounds__(256) void gemm_out_k(
    const u16* __restrict__ AO, const void* __restrict__ woor, const u16* __restrict__ woc,
    const float* __restrict__ bo_f, void* __restrict__ outp, const int* __restrict__ flagp) {
  const int isf32 = *flagp;
  const u16* A = AO;
  const u16* W = isf32 ? woc : (const u16*)woor;
  __shared__ __align__(16) u16 As[128 * 64];
  __shared__ __align__(16) u16 Bs[128 * 64];
  f32x4 acc[4][4];
  const int m0 = blockIdx.y * 128, n0 = blockIdx.x * 128;
  gemm_core(A, W, m0, n0, As, Bs, acc);

  const int lane = threadIdx.x & 63, wave = threadIdx.x >> 6;
  const int quad = lane >> 4, l16 = lane & 15;
  const int wm = wave >> 1, wn = wave & 1;
#pragma unroll
  for (int mt = 0; mt < 4; ++mt)
#pragma unroll
    for (int r = 0; r < 4; ++r) {
      int row = m0 + wm * 64 + mt * 16 + quad * 4 + r;
#pragma unroll
      for (int nt = 0; nt < 4; ++nt) {
        int col = n0 + wn * 64 + nt * 16 + l16;
        float v = acc[mt][nt][r] + bo_f[col];
        if (isf32) ((float*)outp)[(size_t)row * E_ + col] = v;
        else ((u16*)outp)[(size_t)row * E_ + col] = f2bf(v);
      }
    }
}

// ================= flash attention, S^T formulation =================
// Block = (qt, h, b); 4 waves x 16 q-rows. Each lane owns q-row = q0w + l16.
__global__ __launch_bounds__(256) void attn_st(
    const u16* __restrict__ Qp, const u16* __restrict__ Kp, const u16* __restrict__ VpT,
    const unsigned long long* __restrict__ Mb, const unsigned* __restrict__ allonesp,
    u16* __restrict__ AO) {
  const int qt = blockIdx.x, h = blockIdx.y, b = blockIdx.z;
  const int tid = threadIdx.x;
  const int wave = tid >> 6, lane = tid & 63;
  const int quad = lane >> 4, l16 = lane & 15;
  const size_t bh = ((size_t)b * H_ + h) * (size_t)(L_ * D_);
  const int q0w = qt * 64 + wave * 16;
  const bool aone = (*allonesp) != 0u;

  __shared__ __align__(16) u16 Ks[64 * 64];
  __shared__ __align__(16) u16 Vs[64 * 64];
#if !HAVE_M16
  __shared__ __align__(16) u16 Ps[4][16 * 72];
#endif

  // Q B-fragment (n = q-row = l16), prescaled by 1/32*log2e at projection
  s16x8 bq[2];
  {
    const u16* qp = &Qp[bh + (size_t)(q0w + l16) * D_ + quad * 8];
    bq[0] = *(const s16x8*)qp;
    bq[1] = *(const s16x8*)(qp + 32);
  }

  f32x4 Oacc[4];
#pragma unroll
  for (int nt = 0; nt < 4; ++nt)
#pragma unroll
    for (int u = 0; u < 4; ++u) Oacc[nt][u] = 0.f;
  float m_i = -3.0e38f, l_i = 0.f;

  const int lrow = lane >> 3, lch = (lane & 7) ^ lrow;

  for (int kt = 0; kt < L_ / 64; ++kt) {
    const int k0 = kt * 64;
    __syncthreads();
#pragma unroll
    for (int i = 0; i < 2; ++i) {
      int row = wave * 16 + i * 8 + lrow;
      gl_lds16(&Kp[bh + (size_t)(k0 + row) * D_ + lch * 8], &Ks[(wave * 16 + i * 8) * 64]);
      gl_lds16(&VpT[bh + (size_t)row * L_ + k0 + lch * 8], &Vs[(wave * 16 + i * 8) * 64]);
    }
    __syncthreads();

    // S^T = K . Q^T : st[nt] C-layout -> lane holds S'[q=l16][kk = nt*16 + quad*4 + r]
    f32x4 st[4];
#pragma unroll
    for (int nt = 0; nt < 4; ++nt) {
#pragma unroll
      for (int u = 0; u < 4; ++u) st[nt][u] = 0.f;
#pragma unroll
      for (int ks = 0; ks < 2; ++ks) {
        int row = nt * 16 + l16;
        s16x8 ak = *(const s16x8*)&Ks[row * 64 + (((quad + 4 * ks) ^ (row & 7)) * 8)];
        st[nt] = MFMA32(ak, bq[ks], st[nt]);
      }
    }

    float sv[4][4];
    if (aone) {
#pragma unroll
      for (int nt = 0; nt < 4; ++nt)
#pragma unroll
        for (int r = 0; r < 4; ++r) sv[nt][r] = st[nt][r];
    } else {
      unsigned long long mb = Mb[((size_t)b * L_ + q0w + l16) * (L_ / 64) + kt];
      unsigned long long mq = mb >> (quad * 4);
#pragma unroll
      for (int nt = 0; nt < 4; ++nt)
#pragma unroll
        for (int r = 0; r < 4; ++r)
          sv[nt][r] = ((mq >> (nt * 16 + r)) & 1ULL) ? st[nt][r] : MASKC;
    }

    // row max (own 16, then across 4 quads)
    float mx = sv[0][0];
#pragma unroll
    for (int nt = 0; nt < 4; ++nt)
#pragma unroll
      for (int r = 0; r < 4; ++r) mx = fmaxf(mx, sv[nt][r]);
    mx = fmaxf(mx, __shfl_xor(mx, 16));
    mx = fmaxf(mx, __shfl_xor(mx, 32));
    float newm = fmaxf(m_i, mx);
    float alpha = exp2f(m_i - newm);

    float p[4][4];
    float rs = 0.f;
#pragma unroll
    for (int nt = 0; nt < 4; ++nt)
#pragma unroll
      for (int r = 0; r < 4; ++r) {
        float e = exp2f(sv[nt][r] - newm);
        p[nt][r] = e;
        rs += e;
      }
    rs += __shfl_xor(rs, 16);
    rs += __shfl_xor(rs, 32);
    l_i = l_i * alpha + rs;
    m_i = newm;

    // rescale O (rows live at q = quad*4 + r; alpha lives at lane l16=q)
#pragma unroll
    for (int r = 0; r < 4; ++r) {
      float aO = bperm_f((quad * 4 + r) * 4, alpha);
      Oacc[0][r] *= aO; Oacc[1][r] *= aO; Oacc[2][r] *= aO; Oacc[3][r] *= aO;
    }

#if HAVE_M16
    // PV via 16x16x16: p IS the A-fragment (m=l16=q, k=quad*4+r) for each 16-k block
#pragma unroll
    for (int knt = 0; knt < 4; ++knt) {
      unsigned pk0 = permrne(p[knt][1], p[knt][0]);
      unsigned pk1 = permrne(p[knt][3], p[knt][2]);
      union { uint2v u; s16x4 v; } pa;
      pa.u[0] = pk0; pa.u[1] = pk1;
      const int kkb = knt * 16 + quad * 4;
      const int kch = kkb >> 3, kin = kkb & 7;
#pragma unroll
      for (int nt = 0; nt < 4; ++nt) {
        int row = nt * 16 + l16;
        s16x4 vb = *(const s16x4*)&Vs[row * 64 + ((kch ^ (row & 7)) * 8) + kin];
        Oacc[nt] = MFMA16(pa.v, vb, Oacc[nt]);
      }
    }
#else
    // fallback: P through per-wave LDS into K=32 A-layout
#pragma unroll
    for (int nt = 0; nt < 4; ++nt) {
      uint2v w;
      w[0] = permrne(p[nt][1], p[nt][0]);
      w[1] = permrne(p[nt][3], p[nt][2]);
      *(uint2v*)&Ps[wave][l16 * 72 + nt * 16 + quad * 4] = w;
    }
#pragma unroll
    for (int ks = 0; ks < 2; ++ks) {
      s16x8 pa = *(const s16x8*)&Ps[wave][l16 * 72 + quad * 8 + 32 * ks];
#pragma unroll
      for (int nt = 0; nt < 4; ++nt) {
        int row = nt * 16 + l16;
        s16x8 vb = *(const s16x8*)&Vs[row * 64 + (((quad + 4 * ks) ^ (row & 7)) * 8)];
        Oacc[nt] = MFMA32(pa, vb, Oacc[nt]);
      }
    }
#endif
  }

  // normalize + write AO [B, L, E]; O rows q = quad*4+r, cols d = nt*16+l16
#pragma unroll
  for (int r = 0; r < 4; ++r) {
    float lr = bperm_f((quad * 4 + r) * 4, l_i);
    float inv = 1.0f / lr;
    int row = q0w + quad * 4 + r;
#pragma unroll
    for (int nt = 0; nt < 4; ++nt) {
      int col = h * 64 + nt * 16 + l16;
      AO[((size_t)b * L_ + row) * E_ + col] = f2bf(Oacc[nt][r] * inv);
    }
  }
}

// ======================= LEGACY (round-2) fallback path =======================
__device__ inline u16x8 load8_cvt(const void* base, size_t elem_off, int isf32) {
  if (isf32) {
    const float* p = (const float*)base + elem_off;
    f32x4 lo = *(const f32x4*)p;
    f32x4 hi = *(const f32x4*)(p + 4);
    u16x8 t;
#pragma unroll
    for (int j = 0; j < 4; ++j) { t[j] = f2bf(lo[j]); t[4 + j] = f2bf(hi[j]); }
    return t;
  } else {
    return *((const u16x8*)base + elem_off / 8);
  }
}

template <int QKV>
__global__ __launch_bounds__(256) void gemm128(
    const void* __restrict__ A0, const void* __restrict__ A1, const void* __restrict__ A2,
    const void* __restrict__ W0, const void* __restrict__ W1, const void* __restrict__ W2,
    const void* __restrict__ bias,
    void* __restrict__ C0, u16* __restrict__ C1, u16* __restrict__ C2,
    int M, int N, int Kd, const int* __restrict__ flagp) {
  const void* A = A0; const void* W = W0; void* C = C0;
  if (QKV) {
    if (blockIdx.z == 1) { A = A1; W = W1; C = C1; }
    else if (blockIdx.z == 2) { A = A2; W = W2; C = C2; }
  }
  const int isf32 = *flagp;
  const int aF32 = QKV ? isf32 : 0;
  const int tid = threadIdx.x;
  const int wave = tid >> 6, lane = tid & 63;
  const int quad = lane >> 4, l16 = lane & 15;
  const int wm = wave >> 1, wn = wave & 1;
  const int m0 = blockIdx.y * 128, n0 = blockIdx.x * 128;
  __shared__ u16 As[128 * 32];
  __shared__ u16 Bs[128 * 32];
  f32x4 acc[4][4];
#pragma unroll
  for (int i = 0; i < 4; ++i)
#pragma unroll
    for (int j = 0; j < 4; ++j)
#pragma unroll
      for (int u = 0; u < 4; ++u) acc[i][j][u] = 0.f;
  const int row_s = tid >> 2;
  const int cb_s = tid & 3;
  for (int k0 = 0; k0 < Kd; k0 += 32) {
    __syncthreads();
#pragma unroll
    for (int rr = 0; rr < 2; ++rr) {
      int row = rr * 64 + row_s;
      int sw = (cb_s ^ ((row >> 1) & 3)) * 8;
      *(u16x8*)&As[row * 32 + sw] = load8_cvt(A, (size_t)(m0 + row) * Kd + k0 + cb_s * 8, aF32);
      *(u16x8*)&Bs[row * 32 + sw] = load8_cvt(W, (size_t)(n0 + row) * Kd + k0 + cb_s * 8, isf32);
    }
    __syncthreads();
    s16x8 af[4], bfv[4];
#pragma unroll
    for (int mt = 0; mt < 4; ++mt) {
      int row = wm * 64 + mt * 16 + l16;
      af[mt] = *(const s16x8*)&As[row * 32 + (quad ^ ((row >> 1) & 3)) * 8];
    }
#pragma unroll
    for (int nt = 0; nt < 4; ++nt) {
      int row = wn * 64 + nt * 16 + l16;
      bfv[nt] = *(const s16x8*)&Bs[row * 32 + (quad ^ ((row >> 1) & 3)) * 8];
    }
#pragma unroll
    for (int mt = 0; mt < 4; ++mt)
#pragma unroll
      for (int nt = 0; nt < 4; ++nt)
        acc[mt][nt] = MFMA32(af[mt], bfv[nt], acc[mt][nt]);
  }
#pragma unroll
  for (int mt = 0; mt < 4; ++mt)
#pragma unroll
    for (int r = 0; r < 4; ++r) {
      int row = m0 + wm * 64 + mt * 16 + quad * 4 + r;
#pragma unroll
      for (int nt = 0; nt < 4; ++nt) {
        int col = n0 + wn * 64 + nt * 16 + l16;
        float v = acc[mt][nt][r];
        if (!QKV) {
          v += isf32 ? ((const float*)bias)[col] : bf2f(((const u16*)bias)[col]);
          if (isf32) ((float*)C)[(size_t)row * N + col] = v;
          else ((u16*)C)[(size_t)row * N + col] = f2bf(v);
        } else {
          int bb = row >> 11, l = row & (L_ - 1);
          int hh = col >> 6, d = col & 63;
          ((u16*)C)[(((size_t)bb * H_ + hh) * L_ + l) * D_ + d] = f2bf(v);
        }
      }
    }
}

__global__ __launch_bounds__(256) void attn64(const u16* __restrict__ Qp, const u16* __restrict__ Kp,
                                              const u16* __restrict__ Vp,
                                              const unsigned long long* __restrict__ Mb,
                                              u16* __restrict__ AO) {
  const int qt = blockIdx.x, h = blockIdx.y, b = blockIdx.z;
  const int tid = threadIdx.x;
  const int wave = tid >> 6, lane = tid & 63;
  const int quad = lane >> 4, l16 = lane & 15;
  const size_t bh = ((size_t)b * H_ + h) * (size_t)(L_ * D_);
  const int q0 = qt * 64;
  __shared__ u16 Ksl[64 * 72];
  __shared__ u16 Vtl[64 * 72];
  __shared__ u16 Psl[4][16 * 72];
  s16x8 aq[2];
  {
    int qrow = q0 + wave * 16 + l16;
#pragma unroll
    for (int ks = 0; ks < 2; ++ks)
      aq[ks] = *(const s16x8*)&Qp[bh + (size_t)qrow * D_ + quad * 8 + 32 * ks];
  }
  f32x4 Oacc[4];
#pragma unroll
  for (int nt = 0; nt < 4; ++nt)
#pragma unroll
    for (int u = 0; u < 4; ++u) Oacc[nt][u] = 0.f;
  float m_i[4], l_i[4];
#pragma unroll
  for (int r = 0; r < 4; ++r) { m_i[r] = -3.0e38f; l_i[r] = 0.f; }
  const float invs = 0.03125f;
  const float LOG2E = 1.44269504088896f;
  for (int kt = 0; kt < L_ / 64; ++kt) {
    const int k0 = kt * 64;
    __syncthreads();
#pragma unroll
    for (int rr = 0; rr < 2; ++rr) {
      int row = rr * 32 + (tid >> 3);
      int col = (tid & 7) * 8;
      *(u16x8*)&Ksl[row * 72 + col] = *(const u16x8*)&Kp[bh + (size_t)(k0 + row) * D_ + col];
    }
    {
      int d0 = wave * 16;
#pragma unroll
      for (int half = 0; half < 2; ++half) {
        u16x8 tv = *(const u16x8*)&Vp[bh + (size_t)(k0 + lane) * D_ + d0 + half * 8];
#pragma unroll
        for (int j = 0; j < 8; ++j) Vtl[(d0 + half * 8 + j) * 72 + lane] = tv[j];
      }
    }
    __syncthreads();
    f32x4 sacc[4];
#pragma unroll
    for (int nt = 0; nt < 4; ++nt) {
#pragma unroll
      for (int u = 0; u < 4; ++u) sacc[nt][u] = 0.f;
#pragma unroll
      for (int ks = 0; ks < 2; ++ks) {
        s16x8 bfr = *(const s16x8*)&Ksl[(nt * 16 + l16) * 72 + quad * 8 + 32 * ks];
        sacc[nt] = MFMA32(aq[ks], bfr, sacc[nt]);
      }
    }
    float sv[4][4], alph[4];
#pragma unroll
    for (int r = 0; r < 4; ++r) {
      int row = q0 + wave * 16 + quad * 4 + r;
      unsigned long long mb = Mb[(size_t)(b * L_ + row) * (L_ / 64) + kt];
#pragma unroll
      for (int nt = 0; nt < 4; ++nt) {
        float s = sacc[nt][r] * invs;
        if (!((mb >> (nt * 16 + l16)) & 1ULL)) s = -3.125e18f;
        sv[nt][r] = s;
      }
      float mx = fmaxf(fmaxf(sv[0][r], sv[1][r]), fmaxf(sv[2][r], sv[3][r]));
      mx = fmaxf(mx, __shfl_xor(mx, 1));
      mx = fmaxf(mx, __shfl_xor(mx, 2));
      mx = fmaxf(mx, __shfl_xor(mx, 4));
      mx = fmaxf(mx, __shfl_xor(mx, 8));
      float newm = fmaxf(m_i[r], mx);
      float alpha = exp2f((m_i[r] - newm) * LOG2E);
      float rs = 0.f;
#pragma unroll
      for (int nt = 0; nt < 4; ++nt) {
        float pp = exp2f((sv[nt][r] - newm) * LOG2E);
        rs += pp;
        Psl[wave][(quad * 4 + r) * 72 + nt * 16 + l16] = f2bf(pp);
      }
      rs += __shfl_xor(rs, 1);
      rs += __shfl_xor(rs, 2);
      rs += __shfl_xor(rs, 4);
      rs += __shfl_xor(rs, 8);
      l_i[r] = l_i[r] * alpha + rs;
      m_i[r] = newm;
      alph[r] = alpha;
    }
#pragma unroll
    for (int nt = 0; nt < 4; ++nt)
#pragma unroll
      for (int r = 0; r < 4; ++r) Oacc[nt][r] *= alph[r];
#pragma unroll
    for (int ks = 0; ks < 2; ++ks) {
      s16x8 pa = *(const s16x8*)&Psl[wave][l16 * 72 + quad * 8 + 32 * ks];
#pragma unroll
      for (int nt = 0; nt < 4; ++nt) {
        s16x8 vb = *(const s16x8*)&Vtl[(nt * 16 + l16) * 72 + quad * 8 + 32 * ks];
        Oacc[nt] = MFMA32(pa, vb, Oacc[nt]);
      }
    }
  }
#pragma unroll
  for (int nt = 0; nt < 4; ++nt)
#pragma unroll
    for (int r = 0; r < 4; ++r) {
      int row = q0 + wave * 16 + quad * 4 + r;
      int col = h * 64 + nt * 16 + l16;
      AO[((size_t)b * L_ + row) * E_ + col] = f2bf(Oacc[nt][r] / l_i[r]);
    }
}

// ======================= launch =======================
extern "C" void kernel_launch(void* const* d_in, const int* in_sizes, int n_in,
                              void* d_out, int out_size, void* d_ws, size_t ws_size,
                              hipStream_t stream) {
  const void* queries = d_in[0];
  const void* keys = d_in[1];
  const void* values = d_in[2];
  const int* mask = (const int*)d_in[3];
  const void* Wq = d_in[4];
  const void* Wk = d_in[5];
  const void* Wv = d_in[6];
  const void* Wo = d_in[7];
  const void* bo = d_in[8];

  char* ws = (char*)d_ws;
  const int words = B_ * L_ * (L_ / 64);
  const size_t NEED = 111153408;

  if (ws_size >= NEED) {
    // ---- primary path ----
    const size_t SZQ = (size_t)B_ * L_ * E_ * 2;  // 16 MiB
    const size_t SZW = (size_t)E_ * E_ * 2;       // 2 MiB
    u16* qc = (u16*)(ws + 0);
    u16* kc = (u16*)(ws + SZQ);
    u16* vc = (u16*)(ws + 2 * SZQ);
    u16* wqc = (u16*)(ws + 3 * SZQ);
    u16* wkc = (u16*)(ws + 3 * SZQ + SZW);
    u16* wvc = (u16*)(ws + 3 * SZQ + 2 * SZW);
    u16* woc = (u16*)(ws + 3 * SZQ + 3 * SZW);
    float* bo_f = (float*)(ws + 3 * SZQ + 4 * SZW);
    char* p2 = ws + 3 * SZQ + 4 * SZW + 4096;
    u16* Qp = (u16*)(p2);
    u16* Kp = (u16*)(p2 + SZQ);
    u16* VpT = (u16*)(p2 + 2 * SZQ);
    unsigned long long* Mb = (unsigned long long*)(p2 + 3 * SZQ);
    char* pf = p2 + 3 * SZQ + (size_t)words * 8;
    int* flag = (int*)pf;
    unsigned* gflag = (unsigned*)(pf + 4);
    u16* AO = qc;  // alias: qc dead after gemm_qk, AO written by attn afterwards

    hipLaunchKernelGGL(detect_k, dim3(1), dim3(256), 0, stream, (const u16*)queries, flag);
    hipMemsetAsync(gflag, 1, 4, stream);
    hipLaunchKernelGGL(mask_bits_k, dim3(words / 4), dim3(256), 0, stream, mask, Mb, gflag, words);

    int n8q = (B_ * L_ * E_) / 8, n8w = (E_ * E_) / 8;
    hipLaunchKernelGGL(cvt_bf16_k, dim3(n8q / 256), dim3(256), 0, stream, queries, qc, n8q, flag);
    hipLaunchKernelGGL(cvt_bf16_k, dim3(n8q / 256), dim3(256), 0, stream, keys, kc, n8q, flag);
    hipLaunchKernelGGL(cvt_bf16_k, dim3(n8q / 256), dim3(256), 0, stream, values, vc, n8q, flag);
    hipLaunchKernelGGL(cvt_bf16_k, dim3(n8w / 256), dim3(256), 0, stream, Wq, wqc, n8w, flag);
    hipLaunchKernelGGL(cvt_bf16_k, dim3(n8w / 256), dim3(256), 0, stream, Wk, wkc, n8w, flag);
    hipLaunchKernelGGL(cvt_bf16_k, dim3(n8w / 256), dim3(256), 0, stream, Wv, wvc, n8w, flag);
    hipLaunchKernelGGL(cvt_bf16_k, dim3(n8w / 256), dim3(256), 0, stream, Wo, woc, n8w, flag);
    hipLaunchKernelGGL(cvt_f32_k, dim3(E_ / 256), dim3(256), 0, stream, bo, bo_f, E_, flag);

    hipLaunchKernelGGL(gemm_qk_k, dim3(E_ / 128, (B_ * L_) / 128, 2), dim3(256), 0, stream,
                       queries, keys, Wq, Wk, qc, kc, wqc, wkc, Qp, Kp, flag);
    hipLaunchKernelGGL(gemm_vt_k, dim3((B_ * L_) / 128, E_ / 128, 1), dim3(256), 0, stream,
                       values, Wv, vc, wvc, VpT, flag);
    hipLaunchKernelGGL(attn_st, dim3(L_ / 64, H_, B_), dim3(256), 0, stream,
                       Qp, Kp, VpT, Mb, gflag, AO);
    hipLaunchKernelGGL(gemm_out_k, dim3(E_ / 128, (B_ * L_) / 128, 1), dim3(256), 0, stream,
                       AO, Wo, woc, bo_f, d_out, flag);
  } else {
    // ---- legacy (round-2) path ----
    const size_t SEG = (size_t)B_ * H_ * L_ * D_ * sizeof(u16);
    u16* Qp = (u16*)(ws);
    u16* Kp = (u16*)(ws + SEG);
    u16* Vp = (u16*)(ws + 2 * SEG);
    u16* AO = (u16*)(ws + 3 * SEG);
    int* flag = (int*)(ws + 4 * SEG);
    unsigned* gflag = (unsigned*)(ws + 4 * SEG + 8);
    unsigned long long* Mb = (unsigned long long*)(ws + 4 * SEG + 256);

    hipLaunchKernelGGL(detect_k, dim3(1), dim3(256), 0, stream, (const u16*)queries, flag);
    hipMemsetAsync(gflag, 1, 4, stream);
    hipLaunchKernelGGL(mask_bits_k, dim3(words / 4), dim3(256), 0, stream, mask, Mb, gflag, words);
    dim3 g1(E_ / 128, (B_ * L_) / 128, 3);
    hipLaunchKernelGGL((gemm128<1>), g1, dim3(256), 0, stream,
                       queries, keys, values, Wq, Wk, Wv, (const void*)nullptr,
                       (void*)Qp, Kp, Vp, B_ * L_, E_, E_, flag);
    hipLaunchKernelGGL(attn64, dim3(L_ / 64, H_, B_), dim3(256), 0, stream, Qp, Kp, Vp, Mb, AO);
    dim3 g2(E_ / 128, (B_ * L_) / 128, 1);
    hipLaunchKernelGGL((gemm128<0>), g2, dim3(256), 0, stream,
                       (const void*)AO, (const void*)nullptr, (const void*)nullptr,
                       Wo, (const void*)nullptr, (const void*)nullptr, bo,
                       d_out, (u16*)nullptr, (u16*)nullptr, B_ * L_, E_, E_, flag);
  }
}

// Round 5
// 444.512 us; speedup vs baseline: 1.6466x; 1.0941x over previous
//
#include <hip/hip_runtime.h>
#include <hip/hip_bf16.h>

#define B_ 4
#define L_ 2048
#define E_ 1024
#define H_ 16
#define D_ 64
#define KDIM 1024

typedef unsigned short u16;
typedef unsigned short u16x8 __attribute__((ext_vector_type(8)));
typedef short s16x8 __attribute__((ext_vector_type(8)));
typedef float f32x4 __attribute__((ext_vector_type(4)));
typedef unsigned uint2v __attribute__((ext_vector_type(2)));
typedef __fp16 h16x2 __attribute__((ext_vector_type(2)));
typedef __fp16 h16x4 __attribute__((ext_vector_type(4)));
typedef __fp16 h16x8 __attribute__((ext_vector_type(8)));

#define MFMA32(a, b, c) __builtin_amdgcn_mfma_f32_16x16x32_bf16(a, b, c, 0, 0, 0)
#define MFMA32F(a, b, c) __builtin_amdgcn_mfma_f32_16x16x32_f16(a, b, c, 0, 0, 0)

#if __has_builtin(__builtin_amdgcn_mfma_f32_16x16x16f16)
#define HAVE_F16K16 1
#define MFMA16F(a, b, c) __builtin_amdgcn_mfma_f32_16x16x16f16(a, b, c, 0, 0, 0)
#else
#define HAVE_F16K16 0
#endif

__device__ inline u16 f2bf(float f) {
  union { float f; unsigned u; } v; v.f = f;
  unsigned r = v.u + 0x7fffu + ((v.u >> 16) & 1u);
  return (u16)(r >> 16);
}
__device__ inline float bf2f(u16 h) {
  union { unsigned u; float f; } v; v.u = ((unsigned)h) << 16;
  return v.f;
}
__device__ inline float bperm_f(int byteaddr, float v) {
  return __uint_as_float((unsigned)__builtin_amdgcn_ds_bpermute(byteaddr, (int)__float_as_uint(v)));
}
__device__ inline u16 f2h_bits(float f) {
  union { __fp16 h; u16 u; } c; c.h = (__fp16)f;
  return c.u;
}

typedef __attribute__((address_space(1))) const unsigned as1_u32;
typedef __attribute__((address_space(3))) unsigned as3_u32;
__device__ inline void gl_lds16(const u16* g, u16* l) {
  __builtin_amdgcn_global_load_lds((as1_u32*)g, (as3_u32*)l, 16, 0, 0);
}

#define SCALE_Q 0.045084220f  /* (1/32) * log2(e) */
#define MASKC  -4.508422e18f  /* -1e20 * (1/32) * log2(e) */

// ---------------- dtype detect: f32 (flag=1) vs bf16 (flag=0) ----------------
__global__ __launch_bounds__(256) void detect_k(const u16* __restrict__ q, int* __restrict__ flag) {
  int tid = threadIdx.x;
  int cnt = 0;
  for (int i = tid; i < 4096; i += 256) {
    unsigned e = (q[i] >> 7) & 0xFFu;
    if (e >= 0xC0u) cnt++;
  }
  __shared__ int s[256];
  s[tid] = cnt;
  __syncthreads();
  for (int off = 128; off; off >>= 1) {
    if (tid < off) s[tid] += s[tid + off];
    __syncthreads();
  }
  if (tid == 0) *flag = (s[0] >= 16) ? 1 : 0;
}

// ---------------- mask -> bitmask + all-ones flag ----------------
__global__ __launch_bounds__(256) void mask_bits_k(const int* __restrict__ mask,
                                                   unsigned long long* __restrict__ bits,
                                                   unsigned* __restrict__ gflag, int words) {
  int gw = (int)((blockIdx.x * 256 + threadIdx.x) >> 6);
  int lane = threadIdx.x & 63;
  if (gw >= words) return;
  int mv = mask[(size_t)gw * 64 + lane];
  unsigned long long bal = __ballot(mv != 0);
  if (lane == 0) {
    bits[gw] = bal;
    if (bal != ~0ULL) atomicAnd(gflag, 0u);
  }
}

// ---------------- single merged conversion kernel ----------------
#define CH_ACT (1 << 20)
#define CH_W (1 << 17)
#define CH_TOT (128 + 3 * CH_ACT + 4 * CH_W)
__global__ __launch_bounds__(256) void cvt_all_k(
    const void* __restrict__ q, const void* __restrict__ k, const void* __restrict__ v,
    const void* __restrict__ wq, const void* __restrict__ wk, const void* __restrict__ wv,
    const void* __restrict__ wo, const void* __restrict__ bo,
    u16* __restrict__ qc, u16* __restrict__ kc, u16* __restrict__ vc,
    u16* __restrict__ wqc, u16* __restrict__ wkc, u16* __restrict__ wvc, u16* __restrict__ woc,
    float* __restrict__ bo_f, const int* __restrict__ flagp) {
  int c = blockIdx.x * 256 + threadIdx.x;
  if (c >= CH_TOT) return;
  const int isf32 = *flagp;
  if (c < 128) {
    if (isf32) {
      f32x4 a = *((const f32x4*)bo + c * 2);
      f32x4 b2 = *((const f32x4*)bo + c * 2 + 1);
      *((f32x4*)bo_f + c * 2) = a;
      *((f32x4*)bo_f + c * 2 + 1) = b2;
    } else {
      const u16* s = (const u16*)bo + c * 8;
#pragma unroll
      for (int j = 0; j < 8; ++j) bo_f[c * 8 + j] = bf2f(s[j]);
    }
    return;
  }
  if (!isf32) return;
  c -= 128;
  const void* src;
  u16* dst;
  size_t off;
  if (c < 3 * CH_ACT) {
    int t = c >> 20;
    off = (size_t)(c & (CH_ACT - 1));
    src = t == 0 ? q : (t == 1 ? k : v);
    dst = t == 0 ? qc : (t == 1 ? kc : vc);
  } else {
    int d = c - 3 * CH_ACT;
    int t = d >> 17;
    off = (size_t)(d & (CH_W - 1));
    src = t == 0 ? wq : (t == 1 ? wk : (t == 2 ? wv : wo));
    dst = t == 0 ? wqc : (t == 1 ? wkc : (t == 2 ? wvc : woc));
  }
  const float* s = (const float*)src + off * 8;
  f32x4 a = *(const f32x4*)s;
  f32x4 b2 = *(const f32x4*)(s + 4);
  u16x8 o;
#pragma unroll
  for (int j = 0; j < 4; ++j) { o[j] = f2bf(a[j]); o[4 + j] = f2bf(b2[j]); }
  *((u16x8*)dst + off) = o;
}

// ================= GEMM core: 128x128 tile, BK=64, global_load_lds =================
__device__ inline void gemm_core(const u16* __restrict__ A, const u16* __restrict__ W,
                                 int m0, int n0, u16* AsB, u16* BsB, f32x4 (&acc)[4][4]) {
  const int tid = threadIdx.x;
  const int wave = tid >> 6, lane = tid & 63;
  const int quad = lane >> 4, l16 = lane & 15;
  const int wm = wave >> 1, wn = wave & 1;
  const int lrow = lane >> 3;
  const int lch = (lane & 7) ^ lrow;

#pragma unroll
  for (int i = 0; i < 4; ++i)
#pragma unroll
    for (int j = 0; j < 4; ++j)
#pragma unroll
      for (int u = 0; u < 4; ++u) acc[i][j][u] = 0.f;

  const u16* gA = A + (size_t)(m0 + wave * 32 + lrow) * KDIM + lch * 8;
  const u16* gB = W + (size_t)(n0 + wave * 32 + lrow) * KDIM + lch * 8;

  for (int k0 = 0; k0 < KDIM; k0 += 64) {
    __syncthreads();
#pragma unroll
    for (int i = 0; i < 4; ++i) {
      gl_lds16(gA + (size_t)i * 8 * KDIM + k0, &AsB[(wave * 32 + i * 8) * 64]);
      gl_lds16(gB + (size_t)i * 8 * KDIM + k0, &BsB[(wave * 32 + i * 8) * 64]);
    }
    __syncthreads();
#pragma unroll
    for (int ks = 0; ks < 2; ++ks) {
      s16x8 af[4], bf[4];
#pragma unroll
      for (int mt = 0; mt < 4; ++mt) {
        int row = wm * 64 + mt * 16 + l16;
        af[mt] = *(const s16x8*)&AsB[row * 64 + (((quad + 4 * ks) ^ (row & 7)) * 8)];
      }
#pragma unroll
      for (int nt = 0; nt < 4; ++nt) {
        int row = wn * 64 + nt * 16 + l16;
        bf[nt] = *(const s16x8*)&BsB[row * 64 + (((quad + 4 * ks) ^ (row & 7)) * 8)];
      }
#pragma unroll
      for (int mt = 0; mt < 4; ++mt)
#pragma unroll
        for (int nt = 0; nt < 4; ++nt)
          acc[mt][nt] = MFMA32(af[mt], bf[nt], acc[mt][nt]);
    }
  }
}

// Fused projections. z=0: Q (prescaled, bf16 [B,H,L,D]); z=1: K (bf16 [B,H,L,D]);
// z=2: V^T (f16 bits, [B,H,D,L]) with grid roles swapped.
__global__ __launch_bounds__(256) void gemm_proj_k(
    const void* __restrict__ qor, const void* __restrict__ kor, const void* __restrict__ vor,
    const void* __restrict__ wqor, const void* __restrict__ wkor, const void* __restrict__ wvor,
    const u16* __restrict__ qc, const u16* __restrict__ kc, const u16* __restrict__ vc,
    const u16* __restrict__ wqc, const u16* __restrict__ wkc, const u16* __restrict__ wvc,
    u16* __restrict__ Qp, u16* __restrict__ Kp, u16* __restrict__ VpT,
    const int* __restrict__ flagp) {
  const int isf32 = *flagp;
  const int z = blockIdx.z;
  __shared__ __align__(16) u16 As[128 * 64];
  __shared__ __align__(16) u16 Bs[128 * 64];
  f32x4 acc[4][4];

  const int lane = threadIdx.x & 63, wave = threadIdx.x >> 6;
  const int quad = lane >> 4, l16 = lane & 15;
  const int wm = wave >> 1, wn = wave & 1;

  if (z < 2) {
    const u16* A = z ? (isf32 ? kc : (const u16*)kor) : (isf32 ? qc : (const u16*)qor);
    const u16* W = z ? (isf32 ? wkc : (const u16*)wkor) : (isf32 ? wqc : (const u16*)wqor);
    u16* C = z ? Kp : Qp;
    const float scale = z ? 1.0f : SCALE_Q;
    const int m0 = blockIdx.y * 128, n0 = blockIdx.x * 128;
    gemm_core(A, W, m0, n0, As, Bs, acc);
#pragma unroll
    for (int mt = 0; mt < 4; ++mt)
#pragma unroll
      for (int r = 0; r < 4; ++r) {
        int row = m0 + wm * 64 + mt * 16 + quad * 4 + r;
        int bb = row >> 11, l = row & (L_ - 1);
#pragma unroll
        for (int nt = 0; nt < 4; ++nt) {
          int col = n0 + wn * 64 + nt * 16 + l16;
          int hh = col >> 6, d = col & 63;
          C[(((size_t)bb * H_ + hh) * L_ + l) * D_ + d] = f2bf(acc[mt][nt][r] * scale);
        }
      }
  } else {
    const u16* A = isf32 ? wvc : (const u16*)wvor;    // weight rows (M = 1024)
    const u16* W = isf32 ? vc : (const u16*)vor;      // tokens (N = 8192)
    const int m0 = blockIdx.x * 128, n0 = blockIdx.y * 128;
    gemm_core(A, W, m0, n0, As, Bs, acc);
#pragma unroll
    for (int mt = 0; mt < 4; ++mt)
#pragma unroll
      for (int r = 0; r < 4; ++r) {
        int o = m0 + wm * 64 + mt * 16 + quad * 4 + r;
        int hh = o >> 6, d = o & 63;
#pragma unroll
        for (int nt = 0; nt < 4; ++nt) {
          int t = n0 + wn * 64 + nt * 16 + l16;
          int bb = t >> 11, l = t & (L_ - 1);
          VpT[(((size_t)bb * H_ + hh) * D_ + d) * L_ + l] = f2h_bits(acc[mt][nt][r]);
        }
      }
  }
}

// Output projection + bias; writes d_out in flagged dtype
__global__ __launch_bounds__(256) void gemm_out_k(
    const u16* __restrict__ AO, const void* __restrict__ woor, const u16* __restrict__ woc,
    const float* __restrict__ bo_f, void* __restrict__ outp, const int* __restrict__ flagp) {
  const int isf32 = *flagp;
  const u16* W = isf32 ? woc : (const u16*)woor;
  __shared__ __align__(16) u16 As[128 * 64];
  __shared__ __align__(16) u16 Bs[128 * 64];
  f32x4 acc[4][4];
  const int m0 = blockIdx.y * 128, n0 = blockIdx.x * 128;
  gemm_core(AO, W, m0, n0, As, Bs, acc);

  const int lane = threadIdx.x & 63, wave = threadIdx.x >> 6;
  const int quad = lane >> 4, l16 = lane & 15;
  const int wm = wave >> 1, wn = wave & 1;
#pragma unroll
  for (int mt = 0; mt < 4; ++mt)
#pragma unroll
    for (int r = 0; r < 4; ++r) {
      int row = m0 + wm * 64 + mt * 16 + quad * 4 + r;
#pragma unroll
      for (int nt = 0; nt < 4; ++nt) {
        int col = n0 + wn * 64 + nt * 16 + l16;
        float v = acc[mt][nt][r] + bo_f[col];
        if (isf32) ((float*)outp)[(size_t)row * E_ + col] = v;
        else ((u16*)outp)[(size_t)row * E_ + col] = f2bf(v);
      }
    }
}

// ================= flash attention, S^T formulation, BK=128, fp16 PV =================
__global__ __launch_bounds__(256) void attn_st2(
    const u16* __restrict__ Qp, const u16* __restrict__ Kp, const u16* __restrict__ VpT,
    const unsigned long long* __restrict__ Mb, const unsigned* __restrict__ allonesp,
    u16* __restrict__ AO) {
  const int qt = blockIdx.x, h = blockIdx.y, b = blockIdx.z;
  const int tid = threadIdx.x;
  const int wave = tid >> 6, lane = tid & 63;
  const int quad = lane >> 4, l16 = lane & 15;
  const size_t bh = ((size_t)b * H_ + h) * (size_t)(L_ * D_);
  const int q0w = qt * 64 + wave * 16;
  const bool aone = (*allonesp) != 0u;

  __shared__ __align__(16) u16 Ks[128 * 64];  // bf16 [k][d], 8 chunks/row, XOR swizzled
  __shared__ __align__(16) u16 Vs[64 * 128];  // f16 [d][k], 16 chunks/row, XOR swizzled
#if !HAVE_F16K16
  __shared__ __align__(16) u16 Ps[4][16 * 136];  // f16 per-wave P scratch
#endif

  // Q B-fragment (n = q-row = l16), prescaled by (1/32)*log2e
  s16x8 bq[2];
  {
    const u16* qp = &Qp[bh + (size_t)(q0w + l16) * D_ + quad * 8];
    bq[0] = *(const s16x8*)qp;
    bq[1] = *(const s16x8*)(qp + 32);
  }

  f32x4 Oacc[4];
#pragma unroll
  for (int nt = 0; nt < 4; ++nt)
#pragma unroll
    for (int u = 0; u < 4; ++u) Oacc[nt][u] = 0.f;
  float m_i = -3.0e38f, l_i = 0.f;

  const int lrow = lane >> 3, lch = (lane & 7) ^ lrow;
  const int vd_sub = lane >> 4;
  const int vchp = lane & 15;

  for (int kt = 0; kt < L_ / 128; ++kt) {
    const int k0 = kt * 128;
    __syncthreads();
#pragma unroll
    for (int i = 0; i < 4; ++i) {
      int krow = (wave * 4 + i) * 8 + lrow;
      gl_lds16(&Kp[bh + (size_t)(k0 + krow) * D_ + lch * 8], &Ks[(wave * 4 + i) * 512]);
    }
#pragma unroll
    for (int i = 0; i < 4; ++i) {
      int d = wave * 16 + i * 4 + vd_sub;
      int c = vchp ^ (i * 4 + vd_sub);
      gl_lds16(&VpT[bh + (size_t)d * L_ + k0 + c * 8], &Vs[(wave * 16 + i * 4) * 128]);
    }
    __syncthreads();

    // S^T = K . Q^T : s[knt][r] = S'[q=l16][kk = knt*16 + quad*4 + r]
    float s[8][4];
#pragma unroll
    for (int h2 = 0; h2 < 2; ++h2)
#pragma unroll
      for (int nt = 0; nt < 4; ++nt) {
        f32x4 a = {0.f, 0.f, 0.f, 0.f};
        int row = h2 * 64 + nt * 16 + l16;
#pragma unroll
        for (int ks = 0; ks < 2; ++ks) {
          s16x8 ak = *(const s16x8*)&Ks[row * 64 + (((quad + 4 * ks) ^ (row & 7)) * 8)];
          a = MFMA32(ak, bq[ks], a);
        }
#pragma unroll
        for (int r = 0; r < 4; ++r) s[h2 * 4 + nt][r] = a[r];
      }

    if (!aone) {
      const unsigned long long* mrow = &Mb[((size_t)b * L_ + q0w + l16) * (L_ / 64) + kt * 2];
      unsigned long long mb0 = mrow[0] >> (quad * 4);
      unsigned long long mb1 = mrow[1] >> (quad * 4);
#pragma unroll
      for (int h2 = 0; h2 < 2; ++h2) {
        unsigned long long mb = h2 ? mb1 : mb0;
#pragma unroll
        for (int nt = 0; nt < 4; ++nt)
#pragma unroll
          for (int r = 0; r < 4; ++r)
            if (!((mb >> (nt * 16 + r)) & 1ULL)) s[h2 * 4 + nt][r] = MASKC;
      }
    }

    // online softmax over 128 scores (log2 domain)
    float mx = s[0][0];
#pragma unroll
    for (int knt = 0; knt < 8; ++knt)
#pragma unroll
      for (int r = 0; r < 4; ++r) mx = fmaxf(mx, s[knt][r]);
    mx = fmaxf(mx, __shfl_xor(mx, 16));
    mx = fmaxf(mx, __shfl_xor(mx, 32));
    float newm = fmaxf(m_i, mx);
    float alpha = __builtin_amdgcn_exp2f(m_i - newm);

    float rs = 0.f;
#pragma unroll
    for (int knt = 0; knt < 8; ++knt) {
      float t0 = 0.f;
#pragma unroll
      for (int r = 0; r < 4; ++r) {
        float e = __builtin_amdgcn_exp2f(s[knt][r] - newm);
        s[knt][r] = e;
        t0 += e;
      }
      rs += t0;
    }
    rs += __shfl_xor(rs, 16);
    rs += __shfl_xor(rs, 32);
    l_i = l_i * alpha + rs;
    m_i = newm;

    // rescale O (rows q = quad*4+r; alpha lives at lane l16=q)
#pragma unroll
    for (int r = 0; r < 4; ++r) {
      float aO = bperm_f((quad * 4 + r) * 4, alpha);
      Oacc[0][r] *= aO; Oacc[1][r] *= aO; Oacc[2][r] *= aO; Oacc[3][r] *= aO;
    }

#if HAVE_F16K16
    // O += P V via 16x16x16 f16: p IS the A-fragment (m=l16=q, k=quad*4+r)
#pragma unroll
    for (int knt = 0; knt < 8; ++knt) {
      union { h16x2 h2[2]; h16x4 v4; } pu;
      pu.h2[0] = __builtin_amdgcn_cvt_pkrtz(s[knt][0], s[knt][1]);
      pu.h2[1] = __builtin_amdgcn_cvt_pkrtz(s[knt][2], s[knt][3]);
      const int cbase = knt * 2 + (quad >> 1);
      const int sub = (quad & 1) * 4;
#pragma unroll
      for (int nt = 0; nt < 4; ++nt) {
        int d = nt * 16 + l16;
        const __fp16* vp = (const __fp16*)&Vs[d * 128 + ((cbase ^ (d & 15)) * 8) + sub];
        Oacc[nt] = MFMA16F(pu.v4, *(const h16x4*)vp, Oacc[nt]);
      }
    }
#else
    // fallback: P (f16) through per-wave LDS into K=32 A-layout, 16x16x32 f16 MFMA
#pragma unroll
    for (int knt = 0; knt < 8; ++knt) {
      union { h16x2 h2[2]; uint2v u; } pu;
      pu.h2[0] = __builtin_amdgcn_cvt_pkrtz(s[knt][0], s[knt][1]);
      pu.h2[1] = __builtin_amdgcn_cvt_pkrtz(s[knt][2], s[knt][3]);
      *(uint2v*)&Ps[wave][l16 * 136 + knt * 16 + quad * 4] = pu.u;
    }
#pragma unroll
    for (int ks = 0; ks < 4; ++ks) {
      h16x8 pa = *(const h16x8*)&Ps[wave][l16 * 136 + ks * 32 + quad * 8];
#pragma unroll
      for (int nt = 0; nt < 4; ++nt) {
        int d = nt * 16 + l16;
        int c = (ks * 4 + quad) ^ (d & 15);
        h16x8 vb = *(const h16x8*)&Vs[d * 128 + c * 8];
        Oacc[nt] = MFMA32F(pa, vb, Oacc[nt]);
      }
    }
#endif
  }

  // normalize + write AO [B, L, E]
#pragma unroll
  for (int r = 0; r < 4; ++r) {
    float lr = bperm_f((quad * 4 + r) * 4, l_i);
    float inv = 1.0f / lr;
    int row = q0w + quad * 4 + r;
#pragma unroll
    for (int nt = 0; nt < 4; ++nt) {
      int col = h * 64 + nt * 16 + l16;
      AO[((size_t)b * L_ + row) * E_ + col] = f2bf(Oacc[nt][r] * inv);
    }
  }
}

// ======================= LEGACY (round-2) fallback path =======================
__device__ inline u16x8 load8_cvt(const void* base, size_t elem_off, int isf32) {
  if (isf32) {
    const float* p = (const float*)base + elem_off;
    f32x4 lo = *(const f32x4*)p;
    f32x4 hi = *(const f32x4*)(p + 4);
    u16x8 t;
#pragma unroll
    for (int j = 0; j < 4; ++j) { t[j] = f2bf(lo[j]); t[4 + j] = f2bf(hi[j]); }
    return t;
  } else {
    return *((const u16x8*)base + elem_off / 8);
  }
}

template <int QKV>
__global__ __launch_bounds__(256) void gemm128(
    const void* __restrict__ A0, const void* __restrict__ A1, const void* __restrict__ A2,
    const void* __restrict__ W0, const void* __restrict__ W1, const void* __restrict__ W2,
    const void* __restrict__ bias,
    void* __restrict__ C0, u16* __restrict__ C1, u16* __restrict__ C2,
    int M, int N, int Kd, const int* __restrict__ flagp) {
  const void* A = A0; const void* W = W0; void* C = C0;
  if (QKV) {
    if (blockIdx.z == 1) { A = A1; W = W1; C = C1; }
    else if (blockIdx.z == 2) { A = A2; W = W2; C = C2; }
  }
  const int isf32 = *flagp;
  const int aF32 = QKV ? isf32 : 0;
  const int tid = threadIdx.x;
  const int wave = tid >> 6, lane = tid & 63;
  const int quad = lane >> 4, l16 = lane & 15;
  const int wm = wave >> 1, wn = wave & 1;
  const int m0 = blockIdx.y * 128, n0 = blockIdx.x * 128;
  __shared__ u16 As[128 * 32];
  __shared__ u16 Bs[128 * 32];
  f32x4 acc[4][4];
#pragma unroll
  for (int i = 0; i < 4; ++i)
#pragma unroll
    for (int j = 0; j < 4; ++j)
#pragma unroll
      for (int u = 0; u < 4; ++u) acc[i][j][u] = 0.f;
  const int row_s = tid >> 2;
  const int cb_s = tid & 3;
  for (int k0 = 0; k0 < Kd; k0 += 32) {
    __syncthreads();
#pragma unroll
    for (int rr = 0; rr < 2; ++rr) {
      int row = rr * 64 + row_s;
      int sw = (cb_s ^ ((row >> 1) & 3)) * 8;
      *(u16x8*)&As[row * 32 + sw] = load8_cvt(A, (size_t)(m0 + row) * Kd + k0 + cb_s * 8, aF32);
      *(u16x8*)&Bs[row * 32 + sw] = load8_cvt(W, (size_t)(n0 + row) * Kd + k0 + cb_s * 8, isf32);
    }
    __syncthreads();
    s16x8 af[4], bfv[4];
#pragma unroll
    for (int mt = 0; mt < 4; ++mt) {
      int row = wm * 64 + mt * 16 + l16;
      af[mt] = *(const s16x8*)&As[row * 32 + (quad ^ ((row >> 1) & 3)) * 8];
    }
#pragma unroll
    for (int nt = 0; nt < 4; ++nt) {
      int row = wn * 64 + nt * 16 + l16;
      bfv[nt] = *(const s16x8*)&Bs[row * 32 + (quad ^ ((row >> 1) & 3)) * 8];
    }
#pragma unroll
    for (int mt = 0; mt < 4; ++mt)
#pragma unroll
      for (int nt = 0; nt < 4; ++nt)
        acc[mt][nt] = MFMA32(af[mt], bfv[nt], acc[mt][nt]);
  }
#pragma unroll
  for (int mt = 0; mt < 4; ++mt)
#pragma unroll
    for (int r = 0; r < 4; ++r) {
      int row = m0 + wm * 64 + mt * 16 + quad * 4 + r;
#pragma unroll
      for (int nt = 0; nt < 4; ++nt) {
        int col = n0 + wn * 64 + nt * 16 + l16;
        float v = acc[mt][nt][r];
        if (!QKV) {
          v += isf32 ? ((const float*)bias)[col] : bf2f(((const u16*)bias)[col]);
          if (isf32) ((float*)C)[(size_t)row * N + col] = v;
          else ((u16*)C)[(size_t)row * N + col] = f2bf(v);
        } else {
          int bb = row >> 11, l = row & (L_ - 1);
          int hh = col >> 6, d = col & 63;
          ((u16*)C)[(((size_t)bb * H_ + hh) * L_ + l) * D_ + d] = f2bf(v);
        }
      }
    }
}

__global__ __launch_bounds__(256) void attn64(const u16* __restrict__ Qp, const u16* __restrict__ Kp,
                                              const u16* __restrict__ Vp,
                                              const unsigned long long* __restrict__ Mb,
                                              u16* __restrict__ AO) {
  const int qt = blockIdx.x, h = blockIdx.y, b = blockIdx.z;
  const int tid = threadIdx.x;
  const int wave = tid >> 6, lane = tid & 63;
  const int quad = lane >> 4, l16 = lane & 15;
  const size_t bh = ((size_t)b * H_ + h) * (size_t)(L_ * D_);
  const int q0 = qt * 64;
  __shared__ u16 Ksl[64 * 72];
  __shared__ u16 Vtl[64 * 72];
  __shared__ u16 Psl[4][16 * 72];
  s16x8 aq[2];
  {
    int qrow = q0 + wave * 16 + l16;
#pragma unroll
    for (int ks = 0; ks < 2; ++ks)
      aq[ks] = *(const s16x8*)&Qp[bh + (size_t)qrow * D_ + quad * 8 + 32 * ks];
  }
  f32x4 Oacc[4];
#pragma unroll
  for (int nt = 0; nt < 4; ++nt)
#pragma unroll
    for (int u = 0; u < 4; ++u) Oacc[nt][u] = 0.f;
  float m_i[4], l_i[4];
#pragma unroll
  for (int r = 0; r < 4; ++r) { m_i[r] = -3.0e38f; l_i[r] = 0.f; }
  const float invs = 0.03125f;
  const float LOG2E = 1.44269504088896f;
  for (int kt = 0; kt < L_ / 64; ++kt) {
    const int k0 = kt * 64;
    __syncthreads();
#pragma unroll
    for (int rr = 0; rr < 2; ++rr) {
      int row = rr * 32 + (tid >> 3);
      int col = (tid & 7) * 8;
      *(u16x8*)&Ksl[row * 72 + col] = *(const u16x8*)&Kp[bh + (size_t)(k0 + row) * D_ + col];
    }
    {
      int d0 = wave * 16;
#pragma unroll
      for (int half = 0; half < 2; ++half) {
        u16x8 tv = *(const u16x8*)&Vp[bh + (size_t)(k0 + lane) * D_ + d0 + half * 8];
#pragma unroll
        for (int j = 0; j < 8; ++j) Vtl[(d0 + half * 8 + j) * 72 + lane] = tv[j];
      }
    }
    __syncthreads();
    f32x4 sacc[4];
#pragma unroll
    for (int nt = 0; nt < 4; ++nt) {
#pragma unroll
      for (int u = 0; u < 4; ++u) sacc[nt][u] = 0.f;
#pragma unroll
      for (int ks = 0; ks < 2; ++ks) {
        s16x8 bfr = *(const s16x8*)&Ksl[(nt * 16 + l16) * 72 + quad * 8 + 32 * ks];
        sacc[nt] = MFMA32(aq[ks], bfr, sacc[nt]);
      }
    }
    float sv[4][4], alph[4];
#pragma unroll
    for (int r = 0; r < 4; ++r) {
      int row = q0 + wave * 16 + quad * 4 + r;
      unsigned long long mb = Mb[(size_t)(b * L_ + row) * (L_ / 64) + kt];
#pragma unroll
      for (int nt = 0; nt < 4; ++nt) {
        float s = sacc[nt][r] * invs;
        if (!((mb >> (nt * 16 + l16)) & 1ULL)) s = -3.125e18f;
        sv[nt][r] = s;
      }
      float mx = fmaxf(fmaxf(sv[0][r], sv[1][r]), fmaxf(sv[2][r], sv[3][r]));
      mx = fmaxf(mx, __shfl_xor(mx, 1));
      mx = fmaxf(mx, __shfl_xor(mx, 2));
      mx = fmaxf(mx, __shfl_xor(mx, 4));
      mx = fmaxf(mx, __shfl_xor(mx, 8));
      float newm = fmaxf(m_i[r], mx);
      float alpha = exp2f((m_i[r] - newm) * LOG2E);
      float rs = 0.f;
#pragma unroll
      for (int nt = 0; nt < 4; ++nt) {
        float pp = exp2f((sv[nt][r] - newm) * LOG2E);
        rs += pp;
        Psl[wave][(quad * 4 + r) * 72 + nt * 16 + l16] = f2bf(pp);
      }
      rs += __shfl_xor(rs, 1);
      rs += __shfl_xor(rs, 2);
      rs += __shfl_xor(rs, 4);
      rs += __shfl_xor(rs, 8);
      l_i[r] = l_i[r] * alpha + rs;
      m_i[r] = newm;
      alph[r] = alpha;
    }
#pragma unroll
    for (int nt = 0; nt < 4; ++nt)
#pragma unroll
      for (int r = 0; r < 4; ++r) Oacc[nt][r] *= alph[r];
#pragma unroll
    for (int ks = 0; ks < 2; ++ks) {
      s16x8 pa = *(const s16x8*)&Psl[wave][l16 * 72 + quad * 8 + 32 * ks];
#pragma unroll
      for (int nt = 0; nt < 4; ++nt) {
        s16x8 vb = *(const s16x8*)&Vtl[(nt * 16 + l16) * 72 + quad * 8 + 32 * ks];
        Oacc[nt] = MFMA32(pa, vb, Oacc[nt]);
      }
    }
  }
#pragma unroll
  for (int nt = 0; nt < 4; ++nt)
#pragma unroll
    for (int r = 0; r < 4; ++r) {
      int row = q0 + wave * 16 + quad * 4 + r;
      int col = h * 64 + nt * 16 + l16;
      AO[((size_t)b * L_ + row) * E_ + col] = f2bf(Oacc[nt][r] / l_i[r]);
    }
}

// ======================= launch =======================
extern "C" void kernel_launch(void* const* d_in, const int* in_sizes, int n_in,
                              void* d_out, int out_size, void* d_ws, size_t ws_size,
                              hipStream_t stream) {
  const void* queries = d_in[0];
  const void* keys = d_in[1];
  const void* values = d_in[2];
  const int* mask = (const int*)d_in[3];
  const void* Wq = d_in[4];
  const void* Wk = d_in[5];
  const void* Wv = d_in[6];
  const void* Wo = d_in[7];
  const void* bo = d_in[8];

  char* ws = (char*)d_ws;
  const int words = B_ * L_ * (L_ / 64);
  const size_t NEED = 111153408;

  if (ws_size >= NEED) {
    // ---- primary path ----
    const size_t SZQ = (size_t)B_ * L_ * E_ * 2;  // 16 MiB
    const size_t SZW = (size_t)E_ * E_ * 2;       // 2 MiB
    u16* qc = (u16*)(ws + 0);
    u16* kc = (u16*)(ws + SZQ);
    u16* vc = (u16*)(ws + 2 * SZQ);
    u16* wqc = (u16*)(ws + 3 * SZQ);
    u16* wkc = (u16*)(ws + 3 * SZQ + SZW);
    u16* wvc = (u16*)(ws + 3 * SZQ + 2 * SZW);
    u16* woc = (u16*)(ws + 3 * SZQ + 3 * SZW);
    float* bo_f = (float*)(ws + 3 * SZQ + 4 * SZW);
    char* p2 = ws + 3 * SZQ + 4 * SZW + 4096;
    u16* Qp = (u16*)(p2);
    u16* Kp = (u16*)(p2 + SZQ);
    u16* VpT = (u16*)(p2 + 2 * SZQ);  // f16 bits
    unsigned long long* Mb = (unsigned long long*)(p2 + 3 * SZQ);
    char* pf = p2 + 3 * SZQ + (size_t)words * 8;
    int* flag = (int*)pf;
    unsigned* gflag = (unsigned*)(pf + 4);
    u16* AO = qc;  // alias: qc dead after projections

    hipLaunchKernelGGL(detect_k, dim3(1), dim3(256), 0, stream, (const u16*)queries, flag);
    (void)hipMemsetAsync(gflag, 1, 4, stream);
    hipLaunchKernelGGL(mask_bits_k, dim3(words / 4), dim3(256), 0, stream, mask, Mb, gflag, words);
    hipLaunchKernelGGL(cvt_all_k, dim3((CH_TOT + 255) / 256), dim3(256), 0, stream,
                       queries, keys, values, Wq, Wk, Wv, Wo, bo,
                       qc, kc, vc, wqc, wkc, wvc, woc, bo_f, flag);
    hipLaunchKernelGGL(gemm_proj_k, dim3(E_ / 128, (B_ * L_) / 128, 3), dim3(256), 0, stream,
                       queries, keys, values, Wq, Wk, Wv,
                       qc, kc, vc, wqc, wkc, wvc, Qp, Kp, VpT, flag);
    hipLaunchKernelGGL(attn_st2, dim3(L_ / 64, H_, B_), dim3(256), 0, stream,
                       Qp, Kp, VpT, Mb, gflag, AO);
    hipLaunchKernelGGL(gemm_out_k, dim3(E_ / 128, (B_ * L_) / 128, 1), dim3(256), 0, stream,
                       AO, Wo, woc, bo_f, d_out, flag);
  } else {
    // ---- legacy (round-2) path ----
    const size_t SEG = (size_t)B_ * H_ * L_ * D_ * sizeof(u16);
    u16* Qp = (u16*)(ws);
    u16* Kp = (u16*)(ws + SEG);
    u16* Vp = (u16*)(ws + 2 * SEG);
    u16* AO = (u16*)(ws + 3 * SEG);
    int* flag = (int*)(ws + 4 * SEG);
    unsigned* gflag = (unsigned*)(ws + 4 * SEG + 8);
    unsigned long long* Mb = (unsigned long long*)(ws + 4 * SEG + 256);

    hipLaunchKernelGGL(detect_k, dim3(1), dim3(256), 0, stream, (const u16*)queries, flag);
    (void)hipMemsetAsync(gflag, 1, 4, stream);
    hipLaunchKernelGGL(mask_bits_k, dim3(words / 4), dim3(256), 0, stream, mask, Mb, gflag, words);
    dim3 g1(E_ / 128, (B_ * L_) / 128, 3);
    hipLaunchKernelGGL((gemm128<1>), g1, dim3(256), 0, stream,
                       queries, keys, values, Wq, Wk, Wv, (const void*)nullptr,
                       (void*)Qp, Kp, Vp, B_ * L_, E_, E_, flag);
    hipLaunchKernelGGL(attn64, dim3(L_ / 64, H_, B_), dim3(256), 0, stream, Qp, Kp, Vp, Mb, AO);
    dim3 g2(E_ / 128, (B_ * L_) / 128, 1);
    hipLaunchKernelGGL((gemm128<0>), g2, dim3(256), 0, stream,
                       (const void*)AO, (const void*)nullptr, (const void*)nullptr,
                       Wo, (const void*)nullptr, (const void*)nullptr, bo,
                       d_out, (u16*)nullptr, (u16*)nullptr, B_ * L_, E_, E_, flag);
  }
}

// Round 6
// 441.737 us; speedup vs baseline: 1.6570x; 1.0063x over previous
//
#include <hip/hip_runtime.h>
#include <hip/hip_bf16.h>

#define B_ 4
#define L_ 2048
#define E_ 1024
#define H_ 16
#define D_ 64
#define KDIM 1024

typedef unsigned short u16;
typedef unsigned short u16x8 __attribute__((ext_vector_type(8)));
typedef short s16x8 __attribute__((ext_vector_type(8)));
typedef float f32x4 __attribute__((ext_vector_type(4)));
typedef unsigned uint2v __attribute__((ext_vector_type(2)));
typedef __fp16 h16x2 __attribute__((ext_vector_type(2)));
typedef __fp16 h16x4 __attribute__((ext_vector_type(4)));
typedef __fp16 h16x8 __attribute__((ext_vector_type(8)));

#define MFMA32(a, b, c) __builtin_amdgcn_mfma_f32_16x16x32_bf16(a, b, c, 0, 0, 0)
#define MFMA32F(a, b, c) __builtin_amdgcn_mfma_f32_16x16x32_f16(a, b, c, 0, 0, 0)

#if __has_builtin(__builtin_amdgcn_mfma_f32_16x16x16f16)
#define HAVE_F16K16 1
#define MFMA16F(a, b, c) __builtin_amdgcn_mfma_f32_16x16x16f16(a, b, c, 0, 0, 0)
#else
#define HAVE_F16K16 0
#endif

__device__ inline u16 f2bf(float f) {
  union { float f; unsigned u; } v; v.f = f;
  unsigned r = v.u + 0x7fffu + ((v.u >> 16) & 1u);
  return (u16)(r >> 16);
}
__device__ inline float bf2f(u16 h) {
  union { unsigned u; float f; } v; v.u = ((unsigned)h) << 16;
  return v.f;
}
__device__ inline float bperm_f(int byteaddr, float v) {
  return __uint_as_float((unsigned)__builtin_amdgcn_ds_bpermute(byteaddr, (int)__float_as_uint(v)));
}
__device__ inline u16 f2h_bits(float f) {
  union { __fp16 h; u16 u; } c; c.h = (__fp16)f;
  return c.u;
}

typedef __attribute__((address_space(1))) const unsigned as1_u32;
typedef __attribute__((address_space(3))) unsigned as3_u32;
__device__ inline void gl_lds16(const u16* g, u16* l) {
  __builtin_amdgcn_global_load_lds((as1_u32*)g, (as3_u32*)l, 16, 0, 0);
}

#define SCALE_Q 0.045084220f  /* (1/32) * log2(e) */
#define MASKC  -4.508422e18f  /* -1e20 * (1/32) * log2(e) */

// ---------------- dtype detect: f32 (flag=1) vs bf16 (flag=0) ----------------
__global__ __launch_bounds__(256) void detect_k(const u16* __restrict__ q, int* __restrict__ flag) {
  int tid = threadIdx.x;
  int cnt = 0;
  for (int i = tid; i < 4096; i += 256) {
    unsigned e = (q[i] >> 7) & 0xFFu;
    if (e >= 0xC0u) cnt++;
  }
  __shared__ int s[256];
  s[tid] = cnt;
  __syncthreads();
  for (int off = 128; off; off >>= 1) {
    if (tid < off) s[tid] += s[tid + off];
    __syncthreads();
  }
  if (tid == 0) *flag = (s[0] >= 16) ? 1 : 0;
}

// ---------------- merged prep: mask->bits (+allones flag) AND f32->bf16 conversion --------
#define CH_ACT (1 << 20)
#define CH_W (1 << 17)
#define CH_TOT (128 + 3 * CH_ACT + 4 * CH_W)
#define MBLK ((B_ * L_ * (L_ / 64)) / 4) /* mask blocks: words/4 */
#define CVB ((CH_TOT + 255) / 256)

__global__ __launch_bounds__(256) void prep_k(
    const int* __restrict__ mask, unsigned long long* __restrict__ bits,
    unsigned* __restrict__ gflag,
    const void* __restrict__ q, const void* __restrict__ k, const void* __restrict__ v,
    const void* __restrict__ wq, const void* __restrict__ wk, const void* __restrict__ wv,
    const void* __restrict__ wo, const void* __restrict__ bo,
    u16* __restrict__ qc, u16* __restrict__ kc, u16* __restrict__ vc,
    u16* __restrict__ wqc, u16* __restrict__ wkc, u16* __restrict__ wvc, u16* __restrict__ woc,
    float* __restrict__ bo_f, const int* __restrict__ flagp) {
  int bid = blockIdx.x;
  int tid = threadIdx.x;
  if (bid < MBLK) {
    // ---- mask -> bitmask + all-ones detection ----
    int gw = (bid * 256 + tid) >> 6;
    int lane = tid & 63;
    int mv = mask[(size_t)gw * 64 + lane];
    unsigned long long bal = __ballot(mv != 0);
    if (lane == 0) {
      bits[gw] = bal;
      if (bal != ~0ULL) atomicAnd(gflag, 0u);
    }
    return;
  }
  // ---- conversion ----
  int c = (bid - MBLK) * 256 + tid;
  if (c >= CH_TOT) return;
  const int isf32 = *flagp;
  if (c < 128) {
    if (isf32) {
      f32x4 a = *((const f32x4*)bo + c * 2);
      f32x4 b2 = *((const f32x4*)bo + c * 2 + 1);
      *((f32x4*)bo_f + c * 2) = a;
      *((f32x4*)bo_f + c * 2 + 1) = b2;
    } else {
      const u16* s = (const u16*)bo + c * 8;
#pragma unroll
      for (int j = 0; j < 8; ++j) bo_f[c * 8 + j] = bf2f(s[j]);
    }
    return;
  }
  if (!isf32) return;
  c -= 128;
  const void* src;
  u16* dst;
  size_t off;
  if (c < 3 * CH_ACT) {
    int t = c >> 20;
    off = (size_t)(c & (CH_ACT - 1));
    src = t == 0 ? q : (t == 1 ? k : v);
    dst = t == 0 ? qc : (t == 1 ? kc : vc);
  } else {
    int d = c - 3 * CH_ACT;
    int t = d >> 17;
    off = (size_t)(d & (CH_W - 1));
    src = t == 0 ? wq : (t == 1 ? wk : (t == 2 ? wv : wo));
    dst = t == 0 ? wqc : (t == 1 ? wkc : (t == 2 ? wvc : woc));
  }
  const float* s = (const float*)src + off * 8;
  f32x4 a = *(const f32x4*)s;
  f32x4 b2 = *(const f32x4*)(s + 4);
  u16x8 o;
#pragma unroll
  for (int j = 0; j < 4; ++j) { o[j] = f2bf(a[j]); o[4 + j] = f2bf(b2[j]); }
  *((u16x8*)dst + off) = o;
}

// ================= GEMM core: 128x128 tile, BK=64, global_load_lds =================
__device__ inline void gemm_core(const u16* __restrict__ A, const u16* __restrict__ W,
                                 int m0, int n0, u16* AsB, u16* BsB, f32x4 (&acc)[4][4]) {
  const int tid = threadIdx.x;
  const int wave = tid >> 6, lane = tid & 63;
  const int quad = lane >> 4, l16 = lane & 15;
  const int wm = wave >> 1, wn = wave & 1;
  const int lrow = lane >> 3;
  const int lch = (lane & 7) ^ lrow;

#pragma unroll
  for (int i = 0; i < 4; ++i)
#pragma unroll
    for (int j = 0; j < 4; ++j)
#pragma unroll
      for (int u = 0; u < 4; ++u) acc[i][j][u] = 0.f;

  const u16* gA = A + (size_t)(m0 + wave * 32 + lrow) * KDIM + lch * 8;
  const u16* gB = W + (size_t)(n0 + wave * 32 + lrow) * KDIM + lch * 8;

  for (int k0 = 0; k0 < KDIM; k0 += 64) {
    __syncthreads();
#pragma unroll
    for (int i = 0; i < 4; ++i) {
      gl_lds16(gA + (size_t)i * 8 * KDIM + k0, &AsB[(wave * 32 + i * 8) * 64]);
      gl_lds16(gB + (size_t)i * 8 * KDIM + k0, &BsB[(wave * 32 + i * 8) * 64]);
    }
    __syncthreads();
#pragma unroll
    for (int ks = 0; ks < 2; ++ks) {
      s16x8 af[4], bf[4];
#pragma unroll
      for (int mt = 0; mt < 4; ++mt) {
        int row = wm * 64 + mt * 16 + l16;
        af[mt] = *(const s16x8*)&AsB[row * 64 + (((quad + 4 * ks) ^ (row & 7)) * 8)];
      }
#pragma unroll
      for (int nt = 0; nt < 4; ++nt) {
        int row = wn * 64 + nt * 16 + l16;
        bf[nt] = *(const s16x8*)&BsB[row * 64 + (((quad + 4 * ks) ^ (row & 7)) * 8)];
      }
#pragma unroll
      for (int mt = 0; mt < 4; ++mt)
#pragma unroll
        for (int nt = 0; nt < 4; ++nt)
          acc[mt][nt] = MFMA32(af[mt], bf[nt], acc[mt][nt]);
    }
  }
}

// Fused projections. z=0: Q (prescaled, bf16 [B,H,L,D]); z=1: K (bf16 [B,H,L,D]);
// z=2: V^T (f16 bits, [B,H,D,L]) with grid roles swapped.
__global__ __launch_bounds__(256) void gemm_proj_k(
    const void* __restrict__ qor, const void* __restrict__ kor, const void* __restrict__ vor,
    const void* __restrict__ wqor, const void* __restrict__ wkor, const void* __restrict__ wvor,
    const u16* __restrict__ qc, const u16* __restrict__ kc, const u16* __restrict__ vc,
    const u16* __restrict__ wqc, const u16* __restrict__ wkc, const u16* __restrict__ wvc,
    u16* __restrict__ Qp, u16* __restrict__ Kp, u16* __restrict__ VpT,
    const int* __restrict__ flagp) {
  const int isf32 = *flagp;
  const int z = blockIdx.z;
  __shared__ __align__(16) u16 As[128 * 64];
  __shared__ __align__(16) u16 Bs[128 * 64];
  f32x4 acc[4][4];

  const int lane = threadIdx.x & 63, wave = threadIdx.x >> 6;
  const int quad = lane >> 4, l16 = lane & 15;
  const int wm = wave >> 1, wn = wave & 1;

  if (z < 2) {
    const u16* A = z ? (isf32 ? kc : (const u16*)kor) : (isf32 ? qc : (const u16*)qor);
    const u16* W = z ? (isf32 ? wkc : (const u16*)wkor) : (isf32 ? wqc : (const u16*)wqor);
    u16* C = z ? Kp : Qp;
    const float scale = z ? 1.0f : SCALE_Q;
    const int m0 = blockIdx.y * 128, n0 = blockIdx.x * 128;
    gemm_core(A, W, m0, n0, As, Bs, acc);
#pragma unroll
    for (int mt = 0; mt < 4; ++mt)
#pragma unroll
      for (int r = 0; r < 4; ++r) {
        int row = m0 + wm * 64 + mt * 16 + quad * 4 + r;
        int bb = row >> 11, l = row & (L_ - 1);
#pragma unroll
        for (int nt = 0; nt < 4; ++nt) {
          int col = n0 + wn * 64 + nt * 16 + l16;
          int hh = col >> 6, d = col & 63;
          C[(((size_t)bb * H_ + hh) * L_ + l) * D_ + d] = f2bf(acc[mt][nt][r] * scale);
        }
      }
  } else {
    const u16* A = isf32 ? wvc : (const u16*)wvor;    // weight rows (M = 1024)
    const u16* W = isf32 ? vc : (const u16*)vor;      // tokens (N = 8192)
    const int m0 = blockIdx.x * 128, n0 = blockIdx.y * 128;
    gemm_core(A, W, m0, n0, As, Bs, acc);
#pragma unroll
    for (int mt = 0; mt < 4; ++mt)
#pragma unroll
      for (int r = 0; r < 4; ++r) {
        int o = m0 + wm * 64 + mt * 16 + quad * 4 + r;
        int hh = o >> 6, d = o & 63;
#pragma unroll
        for (int nt = 0; nt < 4; ++nt) {
          int t = n0 + wn * 64 + nt * 16 + l16;
          int bb = t >> 11, l = t & (L_ - 1);
          VpT[(((size_t)bb * H_ + hh) * D_ + d) * L_ + l] = f2h_bits(acc[mt][nt][r]);
        }
      }
  }
}

// Output projection + bias; writes d_out in flagged dtype
__global__ __launch_bounds__(256) void gemm_out_k(
    const u16* __restrict__ AO, const void* __restrict__ woor, const u16* __restrict__ woc,
    const float* __restrict__ bo_f, void* __restrict__ outp, const int* __restrict__ flagp) {
  const int isf32 = *flagp;
  const u16* W = isf32 ? woc : (const u16*)woor;
  __shared__ __align__(16) u16 As[128 * 64];
  __shared__ __align__(16) u16 Bs[128 * 64];
  f32x4 acc[4][4];
  const int m0 = blockIdx.y * 128, n0 = blockIdx.x * 128;
  gemm_core(AO, W, m0, n0, As, Bs, acc);

  const int lane = threadIdx.x & 63, wave = threadIdx.x >> 6;
  const int quad = lane >> 4, l16 = lane & 15;
  const int wm = wave >> 1, wn = wave & 1;
#pragma unroll
  for (int mt = 0; mt < 4; ++mt)
#pragma unroll
    for (int r = 0; r < 4; ++r) {
      int row = m0 + wm * 64 + mt * 16 + quad * 4 + r;
#pragma unroll
      for (int nt = 0; nt < 4; ++nt) {
        int col = n0 + wn * 64 + nt * 16 + l16;
        float v = acc[mt][nt][r] + bo_f[col];
        if (isf32) ((float*)outp)[(size_t)row * E_ + col] = v;
        else ((u16*)outp)[(size_t)row * E_ + col] = f2bf(v);
      }
    }
}

// ================= flash attention, S^T form, BK=128, f16 PV, MFMA row-sums ===========
__global__ __launch_bounds__(256) void attn_st3(
    const u16* __restrict__ Qp, const u16* __restrict__ Kp, const u16* __restrict__ VpT,
    const unsigned long long* __restrict__ Mb, const unsigned* __restrict__ allonesp,
    u16* __restrict__ AO) {
  const int qt = blockIdx.x, h = blockIdx.y, b = blockIdx.z;
  const int tid = threadIdx.x;
  const int wave = tid >> 6, lane = tid & 63;
  const int quad = lane >> 4, l16 = lane & 15;
  const size_t bh = ((size_t)b * H_ + h) * (size_t)(L_ * D_);
  const int q0w = qt * 64 + wave * 16;
  const bool aone = (*allonesp) != 0u;

  __shared__ __align__(16) u16 Ks[128 * 64];  // bf16 [k][d], 8 chunks/row, XOR swizzled
  __shared__ __align__(16) u16 Vs[64 * 128];  // f16 [d][k], 16 chunks/row, XOR swizzled
#if !HAVE_F16K16
  __shared__ __align__(16) u16 Ps[4][16 * 136];  // f16 per-wave P scratch
#endif

  // Q B-fragment (n = q-row = l16), prescaled by (1/32)*log2e
  s16x8 bq[2];
  {
    const u16* qp = &Qp[bh + (size_t)(q0w + l16) * D_ + quad * 8];
    bq[0] = *(const s16x8*)qp;
    bq[1] = *(const s16x8*)(qp + 32);
  }

  f32x4 Oacc[4];
  f32x4 Racc;  // row-sum accumulator (same C-layout as Oacc): l_i via MFMA ones-trick
#pragma unroll
  for (int nt = 0; nt < 4; ++nt)
#pragma unroll
    for (int u = 0; u < 4; ++u) Oacc[nt][u] = 0.f;
#pragma unroll
  for (int u = 0; u < 4; ++u) Racc[u] = 0.f;
  float m_i = -3.0e38f;

  const h16x4 onesb = {(__fp16)1.f, (__fp16)1.f, (__fp16)1.f, (__fp16)1.f};

  const int lrow = lane >> 3, lch = (lane & 7) ^ lrow;
  const int vd_sub = lane >> 4;
  const int vchp = lane & 15;

  for (int kt = 0; kt < L_ / 128; ++kt) {
    const int k0 = kt * 128;
    __syncthreads();
#pragma unroll
    for (int i = 0; i < 4; ++i) {
      int krow = (wave * 4 + i) * 8 + lrow;
      gl_lds16(&Kp[bh + (size_t)(k0 + krow) * D_ + lch * 8], &Ks[(wave * 4 + i) * 512]);
    }
#pragma unroll
    for (int i = 0; i < 4; ++i) {
      int d = wave * 16 + i * 4 + vd_sub;
      int c = vchp ^ (i * 4 + vd_sub);
      gl_lds16(&VpT[bh + (size_t)d * L_ + k0 + c * 8], &Vs[(wave * 16 + i * 4) * 128]);
    }
    __syncthreads();

    // S^T = K . Q^T : s[knt][r] = S'[q=l16][kk = knt*16 + quad*4 + r]
    float s[8][4];
#pragma unroll
    for (int h2 = 0; h2 < 2; ++h2)
#pragma unroll
      for (int nt = 0; nt < 4; ++nt) {
        f32x4 a = {0.f, 0.f, 0.f, 0.f};
        int row = h2 * 64 + nt * 16 + l16;
#pragma unroll
        for (int ks = 0; ks < 2; ++ks) {
          s16x8 ak = *(const s16x8*)&Ks[row * 64 + (((quad + 4 * ks) ^ (row & 7)) * 8)];
          a = MFMA32(ak, bq[ks], a);
        }
#pragma unroll
        for (int r = 0; r < 4; ++r) s[h2 * 4 + nt][r] = a[r];
      }

    if (!aone) {
      const unsigned long long* mrow = &Mb[((size_t)b * L_ + q0w + l16) * (L_ / 64) + kt * 2];
      unsigned long long mb0 = mrow[0] >> (quad * 4);
      unsigned long long mb1 = mrow[1] >> (quad * 4);
#pragma unroll
      for (int h2 = 0; h2 < 2; ++h2) {
        unsigned long long mb = h2 ? mb1 : mb0;
#pragma unroll
        for (int nt = 0; nt < 4; ++nt)
#pragma unroll
          for (int r = 0; r < 4; ++r)
            if (!((mb >> (nt * 16 + r)) & 1ULL)) s[h2 * 4 + nt][r] = MASKC;
      }
    }

    // tile max over 32 scores, triples -> v_max3_f32
    float mx;
    {
      float t0 = fmaxf(fmaxf(s[0][0], s[0][1]), s[0][2]);
      float t1 = fmaxf(fmaxf(s[0][3], s[1][0]), s[1][1]);
      float t2 = fmaxf(fmaxf(s[1][2], s[1][3]), s[2][0]);
      float t3 = fmaxf(fmaxf(s[2][1], s[2][2]), s[2][3]);
      float t4 = fmaxf(fmaxf(s[3][0], s[3][1]), s[3][2]);
      float t5 = fmaxf(fmaxf(s[3][3], s[4][0]), s[4][1]);
      float t6 = fmaxf(fmaxf(s[4][2], s[4][3]), s[5][0]);
      float t7 = fmaxf(fmaxf(s[5][1], s[5][2]), s[5][3]);
      float t8 = fmaxf(fmaxf(s[6][0], s[6][1]), s[6][2]);
      float t9 = fmaxf(fmaxf(s[6][3], s[7][0]), s[7][1]);
      float ta = fmaxf(s[7][2], s[7][3]);
      float u0 = fmaxf(fmaxf(t0, t1), t2);
      float u1 = fmaxf(fmaxf(t3, t4), t5);
      float u2 = fmaxf(fmaxf(t6, t7), t8);
      float u3 = fmaxf(t9, ta);
      mx = fmaxf(fmaxf(u0, u1), fmaxf(u2, u3));
    }
    mx = fmaxf(mx, __shfl_xor(mx, 16));
    mx = fmaxf(mx, __shfl_xor(mx, 32));

    const float oldm = m_i;
    const float newm = fmaxf(oldm, mx);
    m_i = newm;

    // rescale O & R only when some row's max actually rose (wave-uniform skip)
    if (__ballot(newm > oldm)) {
      float alpha = __builtin_amdgcn_exp2f(oldm - newm);
#pragma unroll
      for (int r = 0; r < 4; ++r) {
        float aO = bperm_f((quad * 4 + r) * 4, alpha);
        Oacc[0][r] *= aO; Oacc[1][r] *= aO; Oacc[2][r] *= aO; Oacc[3][r] *= aO;
        Racc[r] *= aO;
      }
    }

    // exponentiate (log2 domain; Q prescaled)
#pragma unroll
    for (int knt = 0; knt < 8; ++knt)
#pragma unroll
      for (int r = 0; r < 4; ++r)
        s[knt][r] = __builtin_amdgcn_exp2f(s[knt][r] - newm);

#if HAVE_F16K16
    // O += P V ; R += P 1  via 16x16x16 f16 (p IS the A-fragment: m=l16=q, k=quad*4+r)
#pragma unroll
    for (int knt = 0; knt < 8; ++knt) {
      union { h16x2 h2[2]; h16x4 v4; } pu;
      pu.h2[0] = __builtin_amdgcn_cvt_pkrtz(s[knt][0], s[knt][1]);
      pu.h2[1] = __builtin_amdgcn_cvt_pkrtz(s[knt][2], s[knt][3]);
      const int cbase = knt * 2 + (quad >> 1);
      const int sub = (quad & 1) * 4;
#pragma unroll
      for (int nt = 0; nt < 4; ++nt) {
        int d = nt * 16 + l16;
        const __fp16* vp = (const __fp16*)&Vs[d * 128 + ((cbase ^ (d & 15)) * 8) + sub];
        Oacc[nt] = MFMA16F(pu.v4, *(const h16x4*)vp, Oacc[nt]);
      }
      Racc = MFMA16F(pu.v4, onesb, Racc);
    }
#else
    // fallback: P (f16) through per-wave LDS into K=32 A-layout, 16x16x32 f16 MFMA
#pragma unroll
    for (int knt = 0; knt < 8; ++knt) {
      union { h16x2 h2[2]; uint2v u; } pu;
      pu.h2[0] = __builtin_amdgcn_cvt_pkrtz(s[knt][0], s[knt][1]);
      pu.h2[1] = __builtin_amdgcn_cvt_pkrtz(s[knt][2], s[knt][3]);
      *(uint2v*)&Ps[wave][l16 * 136 + knt * 16 + quad * 4] = pu.u;
    }
    const h16x8 ones8 = {(__fp16)1.f, (__fp16)1.f, (__fp16)1.f, (__fp16)1.f,
                         (__fp16)1.f, (__fp16)1.f, (__fp16)1.f, (__fp16)1.f};
#pragma unroll
    for (int ks = 0; ks < 4; ++ks) {
      h16x8 pa = *(const h16x8*)&Ps[wave][l16 * 136 + ks * 32 + quad * 8];
#pragma unroll
      for (int nt = 0; nt < 4; ++nt) {
        int d = nt * 16 + l16;
        int c = (ks * 4 + quad) ^ (d & 15);
        h16x8 vb = *(const h16x8*)&Vs[d * 128 + c * 8];
        Oacc[nt] = MFMA32F(pa, vb, Oacc[nt]);
      }
      Racc = MFMA32F(pa, ones8, Racc);
    }
#endif
  }

  // normalize + write AO [B, L, E]; l_i for row q=quad*4+r is Racc[r] (any col)
#pragma unroll
  for (int r = 0; r < 4; ++r) {
    float inv = 1.0f / Racc[r];
    int row = q0w + quad * 4 + r;
#pragma unroll
    for (int nt = 0; nt < 4; ++nt) {
      int col = h * 64 + nt * 16 + l16;
      AO[((size_t)b * L_ + row) * E_ + col] = f2bf(Oacc[nt][r] * inv);
    }
  }
}

// ======================= LEGACY (round-2) fallback path =======================
__global__ __launch_bounds__(256) void mask_bits_k(const int* __restrict__ mask,
                                                   unsigned long long* __restrict__ bits,
                                                   unsigned* __restrict__ gflag, int words) {
  int gw = (int)((blockIdx.x * 256 + threadIdx.x) >> 6);
  int lane = threadIdx.x & 63;
  if (gw >= words) return;
  int mv = mask[(size_t)gw * 64 + lane];
  unsigned long long bal = __ballot(mv != 0);
  if (lane == 0) {
    bits[gw] = bal;
    if (bal != ~0ULL) atomicAnd(gflag, 0u);
  }
}

__device__ inline u16x8 load8_cvt(const void* base, size_t elem_off, int isf32) {
  if (isf32) {
    const float* p = (const float*)base + elem_off;
    f32x4 lo = *(const f32x4*)p;
    f32x4 hi = *(const f32x4*)(p + 4);
    u16x8 t;
#pragma unroll
    for (int j = 0; j < 4; ++j) { t[j] = f2bf(lo[j]); t[4 + j] = f2bf(hi[j]); }
    return t;
  } else {
    return *((const u16x8*)base + elem_off / 8);
  }
}

template <int QKV>
__global__ __launch_bounds__(256) void gemm128(
    const void* __restrict__ A0, const void* __restrict__ A1, const void* __restrict__ A2,
    const void* __restrict__ W0, const void* __restrict__ W1, const void* __restrict__ W2,
    const void* __restrict__ bias,
    void* __restrict__ C0, u16* __restrict__ C1, u16* __restrict__ C2,
    int M, int N, int Kd, const int* __restrict__ flagp) {
  const void* A = A0; const void* W = W0; void* C = C0;
  if (QKV) {
    if (blockIdx.z == 1) { A = A1; W = W1; C = C1; }
    else if (blockIdx.z == 2) { A = A2; W = W2; C = C2; }
  }
  const int isf32 = *flagp;
  const int aF32 = QKV ? isf32 : 0;
  const int tid = threadIdx.x;
  const int wave = tid >> 6, lane = tid & 63;
  const int quad = lane >> 4, l16 = lane & 15;
  const int wm = wave >> 1, wn = wave & 1;
  const int m0 = blockIdx.y * 128, n0 = blockIdx.x * 128;
  __shared__ u16 As[128 * 32];
  __shared__ u16 Bs[128 * 32];
  f32x4 acc[4][4];
#pragma unroll
  for (int i = 0; i < 4; ++i)
#pragma unroll
    for (int j = 0; j < 4; ++j)
#pragma unroll
      for (int u = 0; u < 4; ++u) acc[i][j][u] = 0.f;
  const int row_s = tid >> 2;
  const int cb_s = tid & 3;
  for (int k0 = 0; k0 < Kd; k0 += 32) {
    __syncthreads();
#pragma unroll
    for (int rr = 0; rr < 2; ++rr) {
      int row = rr * 64 + row_s;
      int sw = (cb_s ^ ((row >> 1) & 3)) * 8;
      *(u16x8*)&As[row * 32 + sw] = load8_cvt(A, (size_t)(m0 + row) * Kd + k0 + cb_s * 8, aF32);
      *(u16x8*)&Bs[row * 32 + sw] = load8_cvt(W, (size_t)(n0 + row) * Kd + k0 + cb_s * 8, isf32);
    }
    __syncthreads();
    s16x8 af[4], bfv[4];
#pragma unroll
    for (int mt = 0; mt < 4; ++mt) {
      int row = wm * 64 + mt * 16 + l16;
      af[mt] = *(const s16x8*)&As[row * 32 + (quad ^ ((row >> 1) & 3)) * 8];
    }
#pragma unroll
    for (int nt = 0; nt < 4; ++nt) {
      int row = wn * 64 + nt * 16 + l16;
      bfv[nt] = *(const s16x8*)&Bs[row * 32 + (quad ^ ((row >> 1) & 3)) * 8];
    }
#pragma unroll
    for (int mt = 0; mt < 4; ++mt)
#pragma unroll
      for (int nt = 0; nt < 4; ++nt)
        acc[mt][nt] = MFMA32(af[mt], bfv[nt], acc[mt][nt]);
  }
#pragma unroll
  for (int mt = 0; mt < 4; ++mt)
#pragma unroll
    for (int r = 0; r < 4; ++r) {
      int row = m0 + wm * 64 + mt * 16 + quad * 4 + r;
#pragma unroll
      for (int nt = 0; nt < 4; ++nt) {
        int col = n0 + wn * 64 + nt * 16 + l16;
        float v = acc[mt][nt][r];
        if (!QKV) {
          v += isf32 ? ((const float*)bias)[col] : bf2f(((const u16*)bias)[col]);
          if (isf32) ((float*)C)[(size_t)row * N + col] = v;
          else ((u16*)C)[(size_t)row * N + col] = f2bf(v);
        } else {
          int bb = row >> 11, l = row & (L_ - 1);
          int hh = col >> 6, d = col & 63;
          ((u16*)C)[(((size_t)bb * H_ + hh) * L_ + l) * D_ + d] = f2bf(v);
        }
      }
    }
}

__global__ __launch_bounds__(256) void attn64(const u16* __restrict__ Qp, const u16* __restrict__ Kp,
                                              const u16* __restrict__ Vp,
                                              const unsigned long long* __restrict__ Mb,
                                              u16* __restrict__ AO) {
  const int qt = blockIdx.x, h = blockIdx.y, b = blockIdx.z;
  const int tid = threadIdx.x;
  const int wave = tid >> 6, lane = tid & 63;
  const int quad = lane >> 4, l16 = lane & 15;
  const size_t bh = ((size_t)b * H_ + h) * (size_t)(L_ * D_);
  const int q0 = qt * 64;
  __shared__ u16 Ksl[64 * 72];
  __shared__ u16 Vtl[64 * 72];
  __shared__ u16 Psl[4][16 * 72];
  s16x8 aq[2];
  {
    int qrow = q0 + wave * 16 + l16;
#pragma unroll
    for (int ks = 0; ks < 2; ++ks)
      aq[ks] = *(const s16x8*)&Qp[bh + (size_t)qrow * D_ + quad * 8 + 32 * ks];
  }
  f32x4 Oacc[4];
#pragma unroll
  for (int nt = 0; nt < 4; ++nt)
#pragma unroll
    for (int u = 0; u < 4; ++u) Oacc[nt][u] = 0.f;
  float m_i[4], l_i[4];
#pragma unroll
  for (int r = 0; r < 4; ++r) { m_i[r] = -3.0e38f; l_i[r] = 0.f; }
  const float invs = 0.03125f;
  const float LOG2E = 1.44269504088896f;
  for (int kt = 0; kt < L_ / 64; ++kt) {
    const int k0 = kt * 64;
    __syncthreads();
#pragma unroll
    for (int rr = 0; rr < 2; ++rr) {
      int row = rr * 32 + (tid >> 3);
      int col = (tid & 7) * 8;
      *(u16x8*)&Ksl[row * 72 + col] = *(const u16x8*)&Kp[bh + (size_t)(k0 + row) * D_ + col];
    }
    {
      int d0 = wave * 16;
#pragma unroll
      for (int half = 0; half < 2; ++half) {
        u16x8 tv = *(const u16x8*)&Vp[bh + (size_t)(k0 + lane) * D_ + d0 + half * 8];
#pragma unroll
        for (int j = 0; j < 8; ++j) Vtl[(d0 + half * 8 + j) * 72 + lane] = tv[j];
      }
    }
    __syncthreads();
    f32x4 sacc[4];
#pragma unroll
    for (int nt = 0; nt < 4; ++nt) {
#pragma unroll
      for (int u = 0; u < 4; ++u) sacc[nt][u] = 0.f;
#pragma unroll
      for (int ks = 0; ks < 2; ++ks) {
        s16x8 bfr = *(const s16x8*)&Ksl[(nt * 16 + l16) * 72 + quad * 8 + 32 * ks];
        sacc[nt] = MFMA32(aq[ks], bfr, sacc[nt]);
      }
    }
    float sv[4][4], alph[4];
#pragma unroll
    for (int r = 0; r < 4; ++r) {
      int row = q0 + wave * 16 + quad * 4 + r;
      unsigned long long mb = Mb[(size_t)(b * L_ + row) * (L_ / 64) + kt];
#pragma unroll
      for (int nt = 0; nt < 4; ++nt) {
        float s = sacc[nt][r] * invs;
        if (!((mb >> (nt * 16 + l16)) & 1ULL)) s = -3.125e18f;
        sv[nt][r] = s;
      }
      float mx = fmaxf(fmaxf(sv[0][r], sv[1][r]), fmaxf(sv[2][r], sv[3][r]));
      mx = fmaxf(mx, __shfl_xor(mx, 1));
      mx = fmaxf(mx, __shfl_xor(mx, 2));
      mx = fmaxf(mx, __shfl_xor(mx, 4));
      mx = fmaxf(mx, __shfl_xor(mx, 8));
      float newm = fmaxf(m_i[r], mx);
      float alpha = exp2f((m_i[r] - newm) * LOG2E);
      float rs = 0.f;
#pragma unroll
      for (int nt = 0; nt < 4; ++nt) {
        float pp = exp2f((sv[nt][r] - newm) * LOG2E);
        rs += pp;
        Psl[wave][(quad * 4 + r) * 72 + nt * 16 + l16] = f2bf(pp);
      }
      rs += __shfl_xor(rs, 1);
      rs += __shfl_xor(rs, 2);
      rs += __shfl_xor(rs, 4);
      rs += __shfl_xor(rs, 8);
      l_i[r] = l_i[r] * alpha + rs;
      m_i[r] = newm;
      alph[r] = alpha;
    }
#pragma unroll
    for (int nt = 0; nt < 4; ++nt)
#pragma unroll
      for (int r = 0; r < 4; ++r) Oacc[nt][r] *= alph[r];
#pragma unroll
    for (int ks = 0; ks < 2; ++ks) {
      s16x8 pa = *(const s16x8*)&Psl[wave][l16 * 72 + quad * 8 + 32 * ks];
#pragma unroll
      for (int nt = 0; nt < 4; ++nt) {
        s16x8 vb = *(const s16x8*)&Vtl[(nt * 16 + l16) * 72 + quad * 8 + 32 * ks];
        Oacc[nt] = MFMA32(pa, vb, Oacc[nt]);
      }
    }
  }
#pragma unroll
  for (int nt = 0; nt < 4; ++nt)
#pragma unroll
    for (int r = 0; r < 4; ++r) {
      int row = q0 + wave * 16 + quad * 4 + r;
      int col = h * 64 + nt * 16 + l16;
      AO[((size_t)b * L_ + row) * E_ + col] = f2bf(Oacc[nt][r] / l_i[r]);
    }
}

// ======================= launch =======================
extern "C" void kernel_launch(void* const* d_in, const int* in_sizes, int n_in,
                              void* d_out, int out_size, void* d_ws, size_t ws_size,
                              hipStream_t stream) {
  const void* queries = d_in[0];
  const void* keys = d_in[1];
  const void* values = d_in[2];
  const int* mask = (const int*)d_in[3];
  const void* Wq = d_in[4];
  const void* Wk = d_in[5];
  const void* Wv = d_in[6];
  const void* Wo = d_in[7];
  const void* bo = d_in[8];

  char* ws = (char*)d_ws;
  const int words = B_ * L_ * (L_ / 64);
  const size_t NEED = 111153408;

  if (ws_size >= NEED) {
    // ---- primary path ----
    const size_t SZQ = (size_t)B_ * L_ * E_ * 2;  // 16 MiB
    const size_t SZW = (size_t)E_ * E_ * 2;       // 2 MiB
    u16* qc = (u16*)(ws + 0);
    u16* kc = (u16*)(ws + SZQ);
    u16* vc = (u16*)(ws + 2 * SZQ);
    u16* wqc = (u16*)(ws + 3 * SZQ);
    u16* wkc = (u16*)(ws + 3 * SZQ + SZW);
    u16* wvc = (u16*)(ws + 3 * SZQ + 2 * SZW);
    u16* woc = (u16*)(ws + 3 * SZQ + 3 * SZW);
    float* bo_f = (float*)(ws + 3 * SZQ + 4 * SZW);
    char* p2 = ws + 3 * SZQ + 4 * SZW + 4096;
    u16* Qp = (u16*)(p2);
    u16* Kp = (u16*)(p2 + SZQ);
    u16* VpT = (u16*)(p2 + 2 * SZQ);  // f16 bits
    unsigned long long* Mb = (unsigned long long*)(p2 + 3 * SZQ);
    char* pf = p2 + 3 * SZQ + (size_t)words * 8;
    int* flag = (int*)pf;
    unsigned* gflag = (unsigned*)(pf + 4);
    u16* AO = qc;  // alias: qc dead after projections

    hipLaunchKernelGGL(detect_k, dim3(1), dim3(256), 0, stream, (const u16*)queries, flag);
    (void)hipMemsetAsync(gflag, 1, 4, stream);
    hipLaunchKernelGGL(prep_k, dim3(MBLK + CVB), dim3(256), 0, stream,
                       mask, Mb, gflag,
                       queries, keys, values, Wq, Wk, Wv, Wo, bo,
                       qc, kc, vc, wqc, wkc, wvc, woc, bo_f, flag);
    hipLaunchKernelGGL(gemm_proj_k, dim3(E_ / 128, (B_ * L_) / 128, 3), dim3(256), 0, stream,
                       queries, keys, values, Wq, Wk, Wv,
                       qc, kc, vc, wqc, wkc, wvc, Qp, Kp, VpT, flag);
    hipLaunchKernelGGL(attn_st3, dim3(L_ / 64, H_, B_), dim3(256), 0, stream,
                       Qp, Kp, VpT, Mb, gflag, AO);
    hipLaunchKernelGGL(gemm_out_k, dim3(E_ / 128, (B_ * L_) / 128, 1), dim3(256), 0, stream,
                       AO, Wo, woc, bo_f, d_out, flag);
  } else {
    // ---- legacy (round-2) path ----
    const size_t SEG = (size_t)B_ * H_ * L_ * D_ * sizeof(u16);
    u16* Qp = (u16*)(ws);
    u16* Kp = (u16*)(ws + SEG);
    u16* Vp = (u16*)(ws + 2 * SEG);
    u16* AO = (u16*)(ws + 3 * SEG);
    int* flag = (int*)(ws + 4 * SEG);
    unsigned* gflag = (unsigned*)(ws + 4 * SEG + 8);
    unsigned long long* Mb = (unsigned long long*)(ws + 4 * SEG + 256);

    hipLaunchKernelGGL(detect_k, dim3(1), dim3(256), 0, stream, (const u16*)queries, flag);
    (void)hipMemsetAsync(gflag, 1, 4, stream);
    hipLaunchKernelGGL(mask_bits_k, dim3(words / 4), dim3(256), 0, stream, mask, Mb, gflag, words);
    dim3 g1(E_ / 128, (B_ * L_) / 128, 3);
    hipLaunchKernelGGL((gemm128<1>), g1, dim3(256), 0, stream,
                       queries, keys, values, Wq, Wk, Wv, (const void*)nullptr,
                       (void*)Qp, Kp, Vp, B_ * L_, E_, E_, flag);
    hipLaunchKernelGGL(attn64, dim3(L_ / 64, H_, B_), dim3(256), 0, stream, Qp, Kp, Vp, Mb, AO);
    dim3 g2(E_ / 128, (B_ * L_) / 128, 1);
    hipLaunchKernelGGL((gemm128<0>), g2, dim3(256), 0, stream,
                       (const void*)AO, (const void*)nullptr, (const void*)nullptr,
                       Wo, (const void*)nullptr, (const void*)nullptr, bo,
                       d_out, (u16*)nullptr, (u16*)nullptr, B_ * L_, E_, E_, flag);
  }
}

// Round 7
// 433.994 us; speedup vs baseline: 1.6866x; 1.0178x over previous
//
#include <hip/hip_runtime.h>
#include <hip/hip_bf16.h>

#define B_ 4
#define L_ 2048
#define E_ 1024
#define H_ 16
#define D_ 64
#define KDIM 1024

typedef unsigned short u16;
typedef unsigned short u16x8 __attribute__((ext_vector_type(8)));
typedef short s16x8 __attribute__((ext_vector_type(8)));
typedef float f32x4 __attribute__((ext_vector_type(4)));
typedef unsigned uint2v __attribute__((ext_vector_type(2)));
typedef __fp16 h16x2 __attribute__((ext_vector_type(2)));
typedef __fp16 h16x4 __attribute__((ext_vector_type(4)));
typedef __fp16 h16x8 __attribute__((ext_vector_type(8)));

#define MFMA32(a, b, c) __builtin_amdgcn_mfma_f32_16x16x32_bf16(a, b, c, 0, 0, 0)
#define MFMA32F(a, b, c) __builtin_amdgcn_mfma_f32_16x16x32_f16(a, b, c, 0, 0, 0)

#if __has_builtin(__builtin_amdgcn_mfma_f32_16x16x16f16)
#define HAVE_F16K16 1
#define MFMA16F(a, b, c) __builtin_amdgcn_mfma_f32_16x16x16f16(a, b, c, 0, 0, 0)
#else
#define HAVE_F16K16 0
#endif

__device__ inline u16 f2bf(float f) {
  union { float f; unsigned u; } v; v.f = f;
  unsigned r = v.u + 0x7fffu + ((v.u >> 16) & 1u);
  return (u16)(r >> 16);
}
__device__ inline float bf2f(u16 h) {
  union { unsigned u; float f; } v; v.u = ((unsigned)h) << 16;
  return v.f;
}
__device__ inline float bperm_f(int byteaddr, float v) {
  return __uint_as_float((unsigned)__builtin_amdgcn_ds_bpermute(byteaddr, (int)__float_as_uint(v)));
}
__device__ inline u16 f2h_bits(float f) {
  union { __fp16 h; u16 u; } c; c.h = (__fp16)f;
  return c.u;
}
__device__ inline float h2f(u16 b) {
  union { u16 u; __fp16 h; } c; c.u = b;
  return (float)c.h;
}

typedef __attribute__((address_space(1))) const unsigned as1_u32;
typedef __attribute__((address_space(3))) unsigned as3_u32;
__device__ inline void gl_lds16(const u16* g, u16* l) {
  __builtin_amdgcn_global_load_lds((as1_u32*)g, (as3_u32*)l, 16, 0, 0);
}

#define SCALE_Q 0.045084220f  /* (1/32) * log2(e) */
#define MASKC  -4.508422e18f  /* -1e20 * (1/32) * log2(e) */

// ---------------- dtype detect (legacy tier only) ----------------
__global__ __launch_bounds__(256) void detect_k(const u16* __restrict__ q, int* __restrict__ flag) {
  int tid = threadIdx.x;
  int cnt = 0;
  for (int i = tid; i < 4096; i += 256) {
    unsigned e = (q[i] >> 7) & 0xFFu;
    if (e >= 0xC0u) cnt++;
  }
  __shared__ int s[256];
  s[tid] = cnt;
  __syncthreads();
  for (int off = 128; off; off >>= 1) {
    if (tid < off) s[tid] += s[tid + off];
    __syncthreads();
  }
  if (tid == 0) *flag = (s[0] >= 16) ? 1 : 0;
}

// ---------------- merged prep: mask->bits (+allones flag) AND self-detecting cvt -------
#define CH_ACT (1 << 20)
#define CH_W (1 << 17)
#define CH_TOT (128 + 3 * CH_ACT + 4 * CH_W)
#define MBLK ((B_ * L_ * (L_ / 64)) / 4)
#define CVB ((CH_TOT + 255) / 256)

__global__ __launch_bounds__(256) void prep_k2(
    const int* __restrict__ mask, unsigned long long* __restrict__ bits,
    unsigned* __restrict__ gflag,
    const void* __restrict__ q, const void* __restrict__ k, const void* __restrict__ v,
    const void* __restrict__ wq, const void* __restrict__ wk, const void* __restrict__ wv,
    const void* __restrict__ wo, const void* __restrict__ bo,
    u16* __restrict__ qc, u16* __restrict__ kc, u16* __restrict__ vc,
    u16* __restrict__ wqc, u16* __restrict__ wkc, u16* __restrict__ wvc, u16* __restrict__ woc,
    float* __restrict__ bo_f, int* __restrict__ flagw) {
  int bid = blockIdx.x;
  int tid = threadIdx.x;
  if (bid < MBLK) {
    int gw = (bid * 256 + tid) >> 6;
    int lane = tid & 63;
    int mv = mask[(size_t)gw * 64 + lane];
    unsigned long long bal = __ballot(mv != 0);
    if (lane == 0) {
      bits[gw] = bal;
      if (bal != ~0ULL) atomicAnd(gflag, 0u);  // gflag init = ws 0xAA poison (nonzero)
    }
    return;
  }
  // local dtype detect: 1024 u16 of queries (L2-cached; f32 -> ~128 hits, bf16 -> 0)
  const u16* qu = (const u16*)q;
  int cnt = 0;
#pragma unroll
  for (int j = 0; j < 4; ++j) {
    unsigned e = (qu[tid * 4 + j] >> 7) & 0xFFu;
    if (e >= 0xC0u) cnt++;
  }
  __shared__ int sred[256];
  sred[tid] = cnt;
  __syncthreads();
  for (int off = 128; off; off >>= 1) {
    if (tid < off) sred[tid] += sred[tid + off];
    __syncthreads();
  }
  const int isf32 = (sred[0] >= 16) ? 1 : 0;
  if (bid == MBLK && tid == 0) *flagw = isf32;  // for the gemm kernels

  int c = (bid - MBLK) * 256 + tid;
  if (c >= CH_TOT) return;
  if (c < 128) {
    if (isf32) {
      f32x4 a = *((const f32x4*)bo + c * 2);
      f32x4 b2 = *((const f32x4*)bo + c * 2 + 1);
      *((f32x4*)bo_f + c * 2) = a;
      *((f32x4*)bo_f + c * 2 + 1) = b2;
    } else {
      const u16* s = (const u16*)bo + c * 8;
#pragma unroll
      for (int j = 0; j < 8; ++j) bo_f[c * 8 + j] = bf2f(s[j]);
    }
    return;
  }
  if (!isf32) return;
  c -= 128;
  const void* src;
  u16* dst;
  size_t off;
  if (c < 3 * CH_ACT) {
    int t = c >> 20;
    off = (size_t)(c & (CH_ACT - 1));
    src = t == 0 ? q : (t == 1 ? k : v);
    dst = t == 0 ? qc : (t == 1 ? kc : vc);
  } else {
    int d = c - 3 * CH_ACT;
    int t = d >> 17;
    off = (size_t)(d & (CH_W - 1));
    src = t == 0 ? wq : (t == 1 ? wk : (t == 2 ? wv : wo));
    dst = t == 0 ? wqc : (t == 1 ? wkc : (t == 2 ? wvc : woc));
  }
  const float* s = (const float*)src + off * 8;
  f32x4 a = *(const f32x4*)s;
  f32x4 b2 = *(const f32x4*)(s + 4);
  u16x8 o;
#pragma unroll
  for (int j = 0; j < 4; ++j) { o[j] = f2bf(a[j]); o[4 + j] = f2bf(b2[j]); }
  *((u16x8*)dst + off) = o;
}

// ================= GEMM core: 128x128 tile, BK=64, global_load_lds =================
__device__ inline void gemm_core(const u16* __restrict__ A, const u16* __restrict__ W,
                                 int m0, int n0, u16* AsB, u16* BsB, f32x4 (&acc)[4][4]) {
  const int tid = threadIdx.x;
  const int wave = tid >> 6, lane = tid & 63;
  const int quad = lane >> 4, l16 = lane & 15;
  const int wm = wave >> 1, wn = wave & 1;
  const int lrow = lane >> 3;
  const int lch = (lane & 7) ^ lrow;

#pragma unroll
  for (int i = 0; i < 4; ++i)
#pragma unroll
    for (int j = 0; j < 4; ++j)
#pragma unroll
      for (int u = 0; u < 4; ++u) acc[i][j][u] = 0.f;

  const u16* gA = A + (size_t)(m0 + wave * 32 + lrow) * KDIM + lch * 8;
  const u16* gB = W + (size_t)(n0 + wave * 32 + lrow) * KDIM + lch * 8;

  for (int k0 = 0; k0 < KDIM; k0 += 64) {
    __syncthreads();
#pragma unroll
    for (int i = 0; i < 4; ++i) {
      gl_lds16(gA + (size_t)i * 8 * KDIM + k0, &AsB[(wave * 32 + i * 8) * 64]);
      gl_lds16(gB + (size_t)i * 8 * KDIM + k0, &BsB[(wave * 32 + i * 8) * 64]);
    }
    __syncthreads();
#pragma unroll
    for (int ks = 0; ks < 2; ++ks) {
      s16x8 af[4], bf[4];
#pragma unroll
      for (int mt = 0; mt < 4; ++mt) {
        int row = wm * 64 + mt * 16 + l16;
        af[mt] = *(const s16x8*)&AsB[row * 64 + (((quad + 4 * ks) ^ (row & 7)) * 8)];
      }
#pragma unroll
      for (int nt = 0; nt < 4; ++nt) {
        int row = wn * 64 + nt * 16 + l16;
        bf[nt] = *(const s16x8*)&BsB[row * 64 + (((quad + 4 * ks) ^ (row & 7)) * 8)];
      }
#pragma unroll
      for (int mt = 0; mt < 4; ++mt)
#pragma unroll
        for (int nt = 0; nt < 4; ++nt)
          acc[mt][nt] = MFMA32(af[mt], bf[nt], acc[mt][nt]);
    }
  }
}

// Fused projections. z=0: Q (prescaled, bf16 [B,H,L,D]); z=1: K; z=2: V^T (f16, [B,H,D,L]).
__global__ __launch_bounds__(256) void gemm_proj_k(
    const void* __restrict__ qor, const void* __restrict__ kor, const void* __restrict__ vor,
    const void* __restrict__ wqor, const void* __restrict__ wkor, const void* __restrict__ wvor,
    const u16* __restrict__ qc, const u16* __restrict__ kc, const u16* __restrict__ vc,
    const u16* __restrict__ wqc, const u16* __restrict__ wkc, const u16* __restrict__ wvc,
    u16* __restrict__ Qp, u16* __restrict__ Kp, u16* __restrict__ VpT,
    const int* __restrict__ flagp) {
  const int isf32 = *flagp;
  const int z = blockIdx.z;
  __shared__ __align__(16) u16 As[128 * 64];
  __shared__ __align__(16) u16 Bs[128 * 64];
  f32x4 acc[4][4];

  const int lane = threadIdx.x & 63, wave = threadIdx.x >> 6;
  const int quad = lane >> 4, l16 = lane & 15;
  const int wm = wave >> 1, wn = wave & 1;

  if (z < 2) {
    const u16* A = z ? (isf32 ? kc : (const u16*)kor) : (isf32 ? qc : (const u16*)qor);
    const u16* W = z ? (isf32 ? wkc : (const u16*)wkor) : (isf32 ? wqc : (const u16*)wqor);
    u16* C = z ? Kp : Qp;
    const float scale = z ? 1.0f : SCALE_Q;
    const int m0 = blockIdx.y * 128, n0 = blockIdx.x * 128;
    gemm_core(A, W, m0, n0, As, Bs, acc);
#pragma unroll
    for (int mt = 0; mt < 4; ++mt)
#pragma unroll
      for (int r = 0; r < 4; ++r) {
        int row = m0 + wm * 64 + mt * 16 + quad * 4 + r;
        int bb = row >> 11, l = row & (L_ - 1);
#pragma unroll
        for (int nt = 0; nt < 4; ++nt) {
          int col = n0 + wn * 64 + nt * 16 + l16;
          int hh = col >> 6, d = col & 63;
          C[(((size_t)bb * H_ + hh) * L_ + l) * D_ + d] = f2bf(acc[mt][nt][r] * scale);
        }
      }
  } else {
    const u16* A = isf32 ? wvc : (const u16*)wvor;
    const u16* W = isf32 ? vc : (const u16*)vor;
    const int m0 = blockIdx.x * 128, n0 = blockIdx.y * 128;
    gemm_core(A, W, m0, n0, As, Bs, acc);
#pragma unroll
    for (int mt = 0; mt < 4; ++mt)
#pragma unroll
      for (int r = 0; r < 4; ++r) {
        int o = m0 + wm * 64 + mt * 16 + quad * 4 + r;
        int hh = o >> 6, d = o & 63;
#pragma unroll
        for (int nt = 0; nt < 4; ++nt) {
          int t = n0 + wn * 64 + nt * 16 + l16;
          int bb = t >> 11, l = t & (L_ - 1);
          VpT[(((size_t)bb * H_ + hh) * D_ + d) * L_ + l] = f2h_bits(acc[mt][nt][r]);
        }
      }
  }
}

// Output projection + bias
__global__ __launch_bounds__(256) void gemm_out_k(
    const u16* __restrict__ AO, const void* __restrict__ woor, const u16* __restrict__ woc,
    const float* __restrict__ bo_f, void* __restrict__ outp, const int* __restrict__ flagp) {
  const int isf32 = *flagp;
  const u16* W = isf32 ? woc : (const u16*)woor;
  __shared__ __align__(16) u16 As[128 * 64];
  __shared__ __align__(16) u16 Bs[128 * 64];
  f32x4 acc[4][4];
  const int m0 = blockIdx.y * 128, n0 = blockIdx.x * 128;
  gemm_core(AO, W, m0, n0, As, Bs, acc);

  const int lane = threadIdx.x & 63, wave = threadIdx.x >> 6;
  const int quad = lane >> 4, l16 = lane & 15;
  const int wm = wave >> 1, wn = wave & 1;
#pragma unroll
  for (int mt = 0; mt < 4; ++mt)
#pragma unroll
    for (int r = 0; r < 4; ++r) {
      int row = m0 + wm * 64 + mt * 16 + quad * 4 + r;
#pragma unroll
      for (int nt = 0; nt < 4; ++nt) {
        int col = n0 + wn * 64 + nt * 16 + l16;
        float v = acc[mt][nt][r] + bo_f[col];
        if (isf32) ((float*)outp)[(size_t)row * E_ + col] = v;
        else ((u16*)outp)[(size_t)row * E_ + col] = f2bf(v);
      }
    }
}

// ============== split-K flash attention: 2 segments, unnormalized O' + (m,l) stats =========
// Block = (qt|seg, h, b); 4 waves x 16 q-rows; seg covers k in [seg*1024, seg*1024+1024).
__global__ __launch_bounds__(256, 4) void attn_sp(
    const u16* __restrict__ Qp, const u16* __restrict__ Kp, const u16* __restrict__ VpT,
    const unsigned long long* __restrict__ Mb, const unsigned* __restrict__ allonesp,
    u16* __restrict__ Os0, u16* __restrict__ Os1,
    float* __restrict__ m0a, float* __restrict__ l0a,
    float* __restrict__ m1a, float* __restrict__ l1a) {
  const int qt = blockIdx.x & 31, seg = blockIdx.x >> 5;
  const int h = blockIdx.y, b = blockIdx.z;
  const int tid = threadIdx.x;
  const int wave = tid >> 6, lane = tid & 63;
  const int quad = lane >> 4, l16 = lane & 15;
  const size_t bh = ((size_t)b * H_ + h) * (size_t)(L_ * D_);
  const int q0w = qt * 64 + wave * 16;
  const bool aone = (*allonesp) != 0u;

  __shared__ __align__(16) u16 Ks[128 * 64];
  __shared__ __align__(16) u16 Vs[64 * 128];
#if !HAVE_F16K16
  __shared__ __align__(16) u16 Ps[4][16 * 136];
#endif

  s16x8 bq[2];
  {
    const u16* qp = &Qp[bh + (size_t)(q0w + l16) * D_ + quad * 8];
    bq[0] = *(const s16x8*)qp;
    bq[1] = *(const s16x8*)(qp + 32);
  }

  f32x4 Oacc[4];
  f32x4 Racc;
#pragma unroll
  for (int nt = 0; nt < 4; ++nt)
#pragma unroll
    for (int u = 0; u < 4; ++u) Oacc[nt][u] = 0.f;
#pragma unroll
  for (int u = 0; u < 4; ++u) Racc[u] = 0.f;
  float m_i = -3.0e38f;

  const h16x4 onesb = {(__fp16)1.f, (__fp16)1.f, (__fp16)1.f, (__fp16)1.f};

  const int lrow = lane >> 3, lch = (lane & 7) ^ lrow;
  const int vd_sub = lane >> 4;
  const int vchp = lane & 15;

  for (int kt = 0; kt < 8; ++kt) {
    const int ktg = seg * 8 + kt;
    const int k0 = ktg * 128;
    __syncthreads();
#pragma unroll
    for (int i = 0; i < 4; ++i) {
      int krow = (wave * 4 + i) * 8 + lrow;
      gl_lds16(&Kp[bh + (size_t)(k0 + krow) * D_ + lch * 8], &Ks[(wave * 4 + i) * 512]);
    }
#pragma unroll
    for (int i = 0; i < 4; ++i) {
      int d = wave * 16 + i * 4 + vd_sub;
      int c = vchp ^ (i * 4 + vd_sub);
      gl_lds16(&VpT[bh + (size_t)d * L_ + k0 + c * 8], &Vs[(wave * 16 + i * 4) * 128]);
    }
    __syncthreads();

    float s[8][4];
#pragma unroll
    for (int h2 = 0; h2 < 2; ++h2)
#pragma unroll
      for (int nt = 0; nt < 4; ++nt) {
        f32x4 a = {0.f, 0.f, 0.f, 0.f};
        int row = h2 * 64 + nt * 16 + l16;
#pragma unroll
        for (int ks = 0; ks < 2; ++ks) {
          s16x8 ak = *(const s16x8*)&Ks[row * 64 + (((quad + 4 * ks) ^ (row & 7)) * 8)];
          a = MFMA32(ak, bq[ks], a);
        }
#pragma unroll
        for (int r = 0; r < 4; ++r) s[h2 * 4 + nt][r] = a[r];
      }

    if (!aone) {
      const unsigned long long* mrow = &Mb[((size_t)b * L_ + q0w + l16) * (L_ / 64) + ktg * 2];
      unsigned long long mb0 = mrow[0] >> (quad * 4);
      unsigned long long mb1 = mrow[1] >> (quad * 4);
#pragma unroll
      for (int h2 = 0; h2 < 2; ++h2) {
        unsigned long long mb = h2 ? mb1 : mb0;
#pragma unroll
        for (int nt = 0; nt < 4; ++nt)
#pragma unroll
          for (int r = 0; r < 4; ++r)
            if (!((mb >> (nt * 16 + r)) & 1ULL)) s[h2 * 4 + nt][r] = MASKC;
      }
    }

    float mx;
    {
      float t0 = fmaxf(fmaxf(s[0][0], s[0][1]), s[0][2]);
      float t1 = fmaxf(fmaxf(s[0][3], s[1][0]), s[1][1]);
      float t2 = fmaxf(fmaxf(s[1][2], s[1][3]), s[2][0]);
      float t3 = fmaxf(fmaxf(s[2][1], s[2][2]), s[2][3]);
      float t4 = fmaxf(fmaxf(s[3][0], s[3][1]), s[3][2]);
      float t5 = fmaxf(fmaxf(s[3][3], s[4][0]), s[4][1]);
      float t6 = fmaxf(fmaxf(s[4][2], s[4][3]), s[5][0]);
      float t7 = fmaxf(fmaxf(s[5][1], s[5][2]), s[5][3]);
      float t8 = fmaxf(fmaxf(s[6][0], s[6][1]), s[6][2]);
      float t9 = fmaxf(fmaxf(s[6][3], s[7][0]), s[7][1]);
      float ta = fmaxf(s[7][2], s[7][3]);
      float u0 = fmaxf(fmaxf(t0, t1), t2);
      float u1 = fmaxf(fmaxf(t3, t4), t5);
      float u2 = fmaxf(fmaxf(t6, t7), t8);
      float u3 = fmaxf(t9, ta);
      mx = fmaxf(fmaxf(u0, u1), fmaxf(u2, u3));
    }
    mx = fmaxf(mx, __shfl_xor(mx, 16));
    mx = fmaxf(mx, __shfl_xor(mx, 32));

    const float oldm = m_i;
    const float newm = fmaxf(oldm, mx);
    m_i = newm;

    if (__ballot(newm > oldm)) {
      float alpha = __builtin_amdgcn_exp2f(oldm - newm);
#pragma unroll
      for (int r = 0; r < 4; ++r) {
        float aO = bperm_f((quad * 4 + r) * 4, alpha);
        Oacc[0][r] *= aO; Oacc[1][r] *= aO; Oacc[2][r] *= aO; Oacc[3][r] *= aO;
        Racc[r] *= aO;
      }
    }

#pragma unroll
    for (int knt = 0; knt < 8; ++knt)
#pragma unroll
      for (int r = 0; r < 4; ++r)
        s[knt][r] = __builtin_amdgcn_exp2f(s[knt][r] - newm);

#if HAVE_F16K16
#pragma unroll
    for (int knt = 0; knt < 8; ++knt) {
      union { h16x2 h2[2]; h16x4 v4; } pu;
      pu.h2[0] = __builtin_amdgcn_cvt_pkrtz(s[knt][0], s[knt][1]);
      pu.h2[1] = __builtin_amdgcn_cvt_pkrtz(s[knt][2], s[knt][3]);
      const int cbase = knt * 2 + (quad >> 1);
      const int sub = (quad & 1) * 4;
#pragma unroll
      for (int nt = 0; nt < 4; ++nt) {
        int d = nt * 16 + l16;
        const __fp16* vp = (const __fp16*)&Vs[d * 128 + ((cbase ^ (d & 15)) * 8) + sub];
        Oacc[nt] = MFMA16F(pu.v4, *(const h16x4*)vp, Oacc[nt]);
      }
      Racc = MFMA16F(pu.v4, onesb, Racc);
    }
#else
#pragma unroll
    for (int knt = 0; knt < 8; ++knt) {
      union { h16x2 h2[2]; uint2v u; } pu;
      pu.h2[0] = __builtin_amdgcn_cvt_pkrtz(s[knt][0], s[knt][1]);
      pu.h2[1] = __builtin_amdgcn_cvt_pkrtz(s[knt][2], s[knt][3]);
      *(uint2v*)&Ps[wave][l16 * 136 + knt * 16 + quad * 4] = pu.u;
    }
    const h16x8 ones8 = {(__fp16)1.f, (__fp16)1.f, (__fp16)1.f, (__fp16)1.f,
                         (__fp16)1.f, (__fp16)1.f, (__fp16)1.f, (__fp16)1.f};
#pragma unroll
    for (int ks = 0; ks < 4; ++ks) {
      h16x8 pa = *(const h16x8*)&Ps[wave][l16 * 136 + ks * 32 + quad * 8];
#pragma unroll
      for (int nt = 0; nt < 4; ++nt) {
        int d = nt * 16 + l16;
        int c = (ks * 4 + quad) ^ (d & 15);
        h16x8 vb = *(const h16x8*)&Vs[d * 128 + c * 8];
        Oacc[nt] = MFMA32F(pa, vb, Oacc[nt]);
      }
      Racc = MFMA32F(pa, ones8, Racc);
    }
#endif
  }

  // write unnormalized O' (f16) + stats: m (per-lane row l16), l (Racc[r], row quad*4+r)
  u16* Oseg = seg ? Os1 : Os0;
  float* ma = seg ? m1a : m0a;
  float* la = seg ? l1a : l0a;
  const size_t rowbase = ((size_t)b * H_ + h) * L_ + q0w;
#pragma unroll
  for (int r = 0; r < 4; ++r) {
    size_t ro = (rowbase + quad * 4 + r) * D_;
#pragma unroll
    for (int nt = 0; nt < 4; ++nt)
      Oseg[ro + nt * 16 + l16] = f2h_bits(Oacc[nt][r]);
  }
  if (quad == 0) ma[rowbase + l16] = m_i;
  if (l16 == 0) {
#pragma unroll
    for (int r = 0; r < 4; ++r) la[rowbase + quad * 4 + r] = Racc[r];
  }
}

// merge: AO[b,q,h*64+d] = (w0*O'0 + w1*O'1) / (w0*l0 + w1*l1), w_s = 2^(m_s - max)
__global__ __launch_bounds__(256) void merge_k(
    const u16* __restrict__ O0, const u16* __restrict__ O1,
    const float* __restrict__ m0a, const float* __restrict__ l0a,
    const float* __restrict__ m1a, const float* __restrict__ l1a,
    u16* __restrict__ AO) {
  int gid = blockIdx.x * 256 + threadIdx.x;
  int row = gid >> 3;           // (b*H+h)*L + q
  int dc = (gid & 7) * 8;
  float m0 = m0a[row], l0 = l0a[row], m1 = m1a[row], l1 = l1a[row];
  float M = fmaxf(m0, m1);
  float w0 = __builtin_amdgcn_exp2f(m0 - M);
  float w1 = __builtin_amdgcn_exp2f(m1 - M);
  float inv = 1.0f / (w0 * l0 + w1 * l1);
  float s0 = w0 * inv, s1 = w1 * inv;
  u16x8 a = *(const u16x8*)&O0[(size_t)row * D_ + dc];
  u16x8 b8 = *(const u16x8*)&O1[(size_t)row * D_ + dc];
  u16x8 o;
#pragma unroll
  for (int j = 0; j < 8; ++j) o[j] = f2bf(s0 * h2f(a[j]) + s1 * h2f(b8[j]));
  int b = row >> 15, h = (row >> 11) & 15, q = row & 2047;
  *(u16x8*)&AO[((size_t)b * L_ + q) * E_ + h * 64 + dc] = o;
}

// ================= tier-2 attention (R6, monolithic) =================
__global__ __launch_bounds__(256) void attn_st3(
    const u16* __restrict__ Qp, const u16* __restrict__ Kp, const u16* __restrict__ VpT,
    const unsigned long long* __restrict__ Mb, const unsigned* __restrict__ allonesp,
    u16* __restrict__ AO) {
  const int qt = blockIdx.x, h = blockIdx.y, b = blockIdx.z;
  const int tid = threadIdx.x;
  const int wave = tid >> 6, lane = tid & 63;
  const int quad = lane >> 4, l16 = lane & 15;
  const size_t bh = ((size_t)b * H_ + h) * (size_t)(L_ * D_);
  const int q0w = qt * 64 + wave * 16;
  const bool aone = (*allonesp) != 0u;

  __shared__ __align__(16) u16 Ks[128 * 64];
  __shared__ __align__(16) u16 Vs[64 * 128];
#if !HAVE_F16K16
  __shared__ __align__(16) u16 Ps[4][16 * 136];
#endif

  s16x8 bq[2];
  {
    const u16* qp = &Qp[bh + (size_t)(q0w + l16) * D_ + quad * 8];
    bq[0] = *(const s16x8*)qp;
    bq[1] = *(const s16x8*)(qp + 32);
  }

  f32x4 Oacc[4];
  f32x4 Racc;
#pragma unroll
  for (int nt = 0; nt < 4; ++nt)
#pragma unroll
    for (int u = 0; u < 4; ++u) Oacc[nt][u] = 0.f;
#pragma unroll
  for (int u = 0; u < 4; ++u) Racc[u] = 0.f;
  float m_i = -3.0e38f;

  const h16x4 onesb = {(__fp16)1.f, (__fp16)1.f, (__fp16)1.f, (__fp16)1.f};
  const int lrow = lane >> 3, lch = (lane & 7) ^ lrow;
  const int vd_sub = lane >> 4;
  const int vchp = lane & 15;

  for (int kt = 0; kt < L_ / 128; ++kt) {
    const int k0 = kt * 128;
    __syncthreads();
#pragma unroll
    for (int i = 0; i < 4; ++i) {
      int krow = (wave * 4 + i) * 8 + lrow;
      gl_lds16(&Kp[bh + (size_t)(k0 + krow) * D_ + lch * 8], &Ks[(wave * 4 + i) * 512]);
    }
#pragma unroll
    for (int i = 0; i < 4; ++i) {
      int d = wave * 16 + i * 4 + vd_sub;
      int c = vchp ^ (i * 4 + vd_sub);
      gl_lds16(&VpT[bh + (size_t)d * L_ + k0 + c * 8], &Vs[(wave * 16 + i * 4) * 128]);
    }
    __syncthreads();

    float s[8][4];
#pragma unroll
    for (int h2 = 0; h2 < 2; ++h2)
#pragma unroll
      for (int nt = 0; nt < 4; ++nt) {
        f32x4 a = {0.f, 0.f, 0.f, 0.f};
        int row = h2 * 64 + nt * 16 + l16;
#pragma unroll
        for (int ks = 0; ks < 2; ++ks) {
          s16x8 ak = *(const s16x8*)&Ks[row * 64 + (((quad + 4 * ks) ^ (row & 7)) * 8)];
          a = MFMA32(ak, bq[ks], a);
        }
#pragma unroll
        for (int r = 0; r < 4; ++r) s[h2 * 4 + nt][r] = a[r];
      }

    if (!aone) {
      const unsigned long long* mrow = &Mb[((size_t)b * L_ + q0w + l16) * (L_ / 64) + kt * 2];
      unsigned long long mb0 = mrow[0] >> (quad * 4);
      unsigned long long mb1 = mrow[1] >> (quad * 4);
#pragma unroll
      for (int h2 = 0; h2 < 2; ++h2) {
        unsigned long long mb = h2 ? mb1 : mb0;
#pragma unroll
        for (int nt = 0; nt < 4; ++nt)
#pragma unroll
          for (int r = 0; r < 4; ++r)
            if (!((mb >> (nt * 16 + r)) & 1ULL)) s[h2 * 4 + nt][r] = MASKC;
      }
    }

    float mx = s[0][0];
#pragma unroll
    for (int knt = 0; knt < 8; ++knt)
#pragma unroll
      for (int r = 0; r < 4; ++r) mx = fmaxf(mx, s[knt][r]);
    mx = fmaxf(mx, __shfl_xor(mx, 16));
    mx = fmaxf(mx, __shfl_xor(mx, 32));

    const float oldm = m_i;
    const float newm = fmaxf(oldm, mx);
    m_i = newm;

    if (__ballot(newm > oldm)) {
      float alpha = __builtin_amdgcn_exp2f(oldm - newm);
#pragma unroll
      for (int r = 0; r < 4; ++r) {
        float aO = bperm_f((quad * 4 + r) * 4, alpha);
        Oacc[0][r] *= aO; Oacc[1][r] *= aO; Oacc[2][r] *= aO; Oacc[3][r] *= aO;
        Racc[r] *= aO;
      }
    }

#pragma unroll
    for (int knt = 0; knt < 8; ++knt)
#pragma unroll
      for (int r = 0; r < 4; ++r)
        s[knt][r] = __builtin_amdgcn_exp2f(s[knt][r] - newm);

#if HAVE_F16K16
#pragma unroll
    for (int knt = 0; knt < 8; ++knt) {
      union { h16x2 h2[2]; h16x4 v4; } pu;
      pu.h2[0] = __builtin_amdgcn_cvt_pkrtz(s[knt][0], s[knt][1]);
      pu.h2[1] = __builtin_amdgcn_cvt_pkrtz(s[knt][2], s[knt][3]);
      const int cbase = knt * 2 + (quad >> 1);
      const int sub = (quad & 1) * 4;
#pragma unroll
      for (int nt = 0; nt < 4; ++nt) {
        int d = nt * 16 + l16;
        const __fp16* vp = (const __fp16*)&Vs[d * 128 + ((cbase ^ (d & 15)) * 8) + sub];
        Oacc[nt] = MFMA16F(pu.v4, *(const h16x4*)vp, Oacc[nt]);
      }
      Racc = MFMA16F(pu.v4, onesb, Racc);
    }
#else
#pragma unroll
    for (int knt = 0; knt < 8; ++knt) {
      union { h16x2 h2[2]; uint2v u; } pu;
      pu.h2[0] = __builtin_amdgcn_cvt_pkrtz(s[knt][0], s[knt][1]);
      pu.h2[1] = __builtin_amdgcn_cvt_pkrtz(s[knt][2], s[knt][3]);
      *(uint2v*)&Ps[wave][l16 * 136 + knt * 16 + quad * 4] = pu.u;
    }
    const h16x8 ones8 = {(__fp16)1.f, (__fp16)1.f, (__fp16)1.f, (__fp16)1.f,
                         (__fp16)1.f, (__fp16)1.f, (__fp16)1.f, (__fp16)1.f};
#pragma unroll
    for (int ks = 0; ks < 4; ++ks) {
      h16x8 pa = *(const h16x8*)&Ps[wave][l16 * 136 + ks * 32 + quad * 8];
#pragma unroll
      for (int nt = 0; nt < 4; ++nt) {
        int d = nt * 16 + l16;
        int c = (ks * 4 + quad) ^ (d & 15);
        h16x8 vb = *(const h16x8*)&Vs[d * 128 + c * 8];
        Oacc[nt] = MFMA32F(pa, vb, Oacc[nt]);
      }
      Racc = MFMA32F(pa, ones8, Racc);
    }
#endif
  }

#pragma unroll
  for (int r = 0; r < 4; ++r) {
    float inv = 1.0f / Racc[r];
    int row = q0w + quad * 4 + r;
#pragma unroll
    for (int nt = 0; nt < 4; ++nt) {
      int col = h * 64 + nt * 16 + l16;
      AO[((size_t)b * L_ + row) * E_ + col] = f2bf(Oacc[nt][r] * inv);
    }
  }
}

// ======================= LEGACY (tier-3) =======================
__global__ __launch_bounds__(256) void mask_bits_k(const int* __restrict__ mask,
                                                   unsigned long long* __restrict__ bits,
                                                   unsigned* __restrict__ gflag, int words) {
  int gw = (int)((blockIdx.x * 256 + threadIdx.x) >> 6);
  int lane = threadIdx.x & 63;
  if (gw >= words) return;
  int mv = mask[(size_t)gw * 64 + lane];
  unsigned long long bal = __ballot(mv != 0);
  if (lane == 0) {
    bits[gw] = bal;
    if (bal != ~0ULL) atomicAnd(gflag, 0u);
  }
}

__device__ inline u16x8 load8_cvt(const void* base, size_t elem_off, int isf32) {
  if (isf32) {
    const float* p = (const float*)base + elem_off;
    f32x4 lo = *(const f32x4*)p;
    f32x4 hi = *(const f32x4*)(p + 4);
    u16x8 t;
#pragma unroll
    for (int j = 0; j < 4; ++j) { t[j] = f2bf(lo[j]); t[4 + j] = f2bf(hi[j]); }
    return t;
  } else {
    return *((const u16x8*)base + elem_off / 8);
  }
}

template <int QKV>
__global__ __launch_bounds__(256) void gemm128(
    const void* __restrict__ A0, const void* __restrict__ A1, const void* __restrict__ A2,
    const void* __restrict__ W0, const void* __restrict__ W1, const void* __restrict__ W2,
    const void* __restrict__ bias,
    void* __restrict__ C0, u16* __restrict__ C1, u16* __restrict__ C2,
    int M, int N, int Kd, const int* __restrict__ flagp) {
  const void* A = A0; const void* W = W0; void* C = C0;
  if (QKV) {
    if (blockIdx.z == 1) { A = A1; W = W1; C = C1; }
    else if (blockIdx.z == 2) { A = A2; W = W2; C = C2; }
  }
  const int isf32 = *flagp;
  const int aF32 = QKV ? isf32 : 0;
  const int tid = threadIdx.x;
  const int wave = tid >> 6, lane = tid & 63;
  const int quad = lane >> 4, l16 = lane & 15;
  const int wm = wave >> 1, wn = wave & 1;
  const int m0 = blockIdx.y * 128, n0 = blockIdx.x * 128;
  __shared__ u16 As[128 * 32];
  __shared__ u16 Bs[128 * 32];
  f32x4 acc[4][4];
#pragma unroll
  for (int i = 0; i < 4; ++i)
#pragma unroll
    for (int j = 0; j < 4; ++j)
#pragma unroll
      for (int u = 0; u < 4; ++u) acc[i][j][u] = 0.f;
  const int row_s = tid >> 2;
  const int cb_s = tid & 3;
  for (int k0 = 0; k0 < Kd; k0 += 32) {
    __syncthreads();
#pragma unroll
    for (int rr = 0; rr < 2; ++rr) {
      int row = rr * 64 + row_s;
      int sw = (cb_s ^ ((row >> 1) & 3)) * 8;
      *(u16x8*)&As[row * 32 + sw] = load8_cvt(A, (size_t)(m0 + row) * Kd + k0 + cb_s * 8, aF32);
      *(u16x8*)&Bs[row * 32 + sw] = load8_cvt(W, (size_t)(n0 + row) * Kd + k0 + cb_s * 8, isf32);
    }
    __syncthreads();
    s16x8 af[4], bfv[4];
#pragma unroll
    for (int mt = 0; mt < 4; ++mt) {
      int row = wm * 64 + mt * 16 + l16;
      af[mt] = *(const s16x8*)&As[row * 32 + (quad ^ ((row >> 1) & 3)) * 8];
    }
#pragma unroll
    for (int nt = 0; nt < 4; ++nt) {
      int row = wn * 64 + nt * 16 + l16;
      bfv[nt] = *(const s16x8*)&Bs[row * 32 + (quad ^ ((row >> 1) & 3)) * 8];
    }
#pragma unroll
    for (int mt = 0; mt < 4; ++mt)
#pragma unroll
      for (int nt = 0; nt < 4; ++nt)
        acc[mt][nt] = MFMA32(af[mt], bfv[nt], acc[mt][nt]);
  }
#pragma unroll
  for (int mt = 0; mt < 4; ++mt)
#pragma unroll
    for (int r = 0; r < 4; ++r) {
      int row = m0 + wm * 64 + mt * 16 + quad * 4 + r;
#pragma unroll
      for (int nt = 0; nt < 4; ++nt) {
        int col = n0 + wn * 64 + nt * 16 + l16;
        float v = acc[mt][nt][r];
        if (!QKV) {
          v += isf32 ? ((const float*)bias)[col] : bf2f(((const u16*)bias)[col]);
          if (isf32) ((float*)C)[(size_t)row * N + col] = v;
          else ((u16*)C)[(size_t)row * N + col] = f2bf(v);
        } else {
          int bb = row >> 11, l = row & (L_ - 1);
          int hh = col >> 6, d = col & 63;
          ((u16*)C)[(((size_t)bb * H_ + hh) * L_ + l) * D_ + d] = f2bf(v);
        }
      }
    }
}

__global__ __launch_bounds__(256) void attn64(const u16* __restrict__ Qp, const u16* __restrict__ Kp,
                                              const u16* __restrict__ Vp,
                                              const unsigned long long* __restrict__ Mb,
                                              u16* __restrict__ AO) {
  const int qt = blockIdx.x, h = blockIdx.y, b = blockIdx.z;
  const int tid = threadIdx.x;
  const int wave = tid >> 6, lane = tid & 63;
  const int quad = lane >> 4, l16 = lane & 15;
  const size_t bh = ((size_t)b * H_ + h) * (size_t)(L_ * D_);
  const int q0 = qt * 64;
  __shared__ u16 Ksl[64 * 72];
  __shared__ u16 Vtl[64 * 72];
  __shared__ u16 Psl[4][16 * 72];
  s16x8 aq[2];
  {
    int qrow = q0 + wave * 16 + l16;
#pragma unroll
    for (int ks = 0; ks < 2; ++ks)
      aq[ks] = *(const s16x8*)&Qp[bh + (size_t)qrow * D_ + quad * 8 + 32 * ks];
  }
  f32x4 Oacc[4];
#pragma unroll
  for (int nt = 0; nt < 4; ++nt)
#pragma unroll
    for (int u = 0; u < 4; ++u) Oacc[nt][u] = 0.f;
  float m_i[4], l_i[4];
#pragma unroll
  for (int r = 0; r < 4; ++r) { m_i[r] = -3.0e38f; l_i[r] = 0.f; }
  const float invs = 0.03125f;
  const float LOG2E = 1.44269504088896f;
  for (int kt = 0; kt < L_ / 64; ++kt) {
    const int k0 = kt * 64;
    __syncthreads();
#pragma unroll
    for (int rr = 0; rr < 2; ++rr) {
      int row = rr * 32 + (tid >> 3);
      int col = (tid & 7) * 8;
      *(u16x8*)&Ksl[row * 72 + col] = *(const u16x8*)&Kp[bh + (size_t)(k0 + row) * D_ + col];
    }
    {
      int d0 = wave * 16;
#pragma unroll
      for (int half = 0; half < 2; ++half) {
        u16x8 tv = *(const u16x8*)&Vp[bh + (size_t)(k0 + lane) * D_ + d0 + half * 8];
#pragma unroll
        for (int j = 0; j < 8; ++j) Vtl[(d0 + half * 8 + j) * 72 + lane] = tv[j];
      }
    }
    __syncthreads();
    f32x4 sacc[4];
#pragma unroll
    for (int nt = 0; nt < 4; ++nt) {
#pragma unroll
      for (int u = 0; u < 4; ++u) sacc[nt][u] = 0.f;
#pragma unroll
      for (int ks = 0; ks < 2; ++ks) {
        s16x8 bfr = *(const s16x8*)&Ksl[(nt * 16 + l16) * 72 + quad * 8 + 32 * ks];
        sacc[nt] = MFMA32(aq[ks], bfr, sacc[nt]);
      }
    }
    float sv[4][4], alph[4];
#pragma unroll
    for (int r = 0; r < 4; ++r) {
      int row = q0 + wave * 16 + quad * 4 + r;
      unsigned long long mb = Mb[(size_t)(b * L_ + row) * (L_ / 64) + kt];
#pragma unroll
      for (int nt = 0; nt < 4; ++nt) {
        float s = sacc[nt][r] * invs;
        if (!((mb >> (nt * 16 + l16)) & 1ULL)) s = -3.125e18f;
        sv[nt][r] = s;
      }
      float mx = fmaxf(fmaxf(sv[0][r], sv[1][r]), fmaxf(sv[2][r], sv[3][r]));
      mx = fmaxf(mx, __shfl_xor(mx, 1));
      mx = fmaxf(mx, __shfl_xor(mx, 2));
      mx = fmaxf(mx, __shfl_xor(mx, 4));
      mx = fmaxf(mx, __shfl_xor(mx, 8));
      float newm = fmaxf(m_i[r], mx);
      float alpha = exp2f((m_i[r] - newm) * LOG2E);
      float rs = 0.f;
#pragma unroll
      for (int nt = 0; nt < 4; ++nt) {
        float pp = exp2f((sv[nt][r] - newm) * LOG2E);
        rs += pp;
        Psl[wave][(quad * 4 + r) * 72 + nt * 16 + l16] = f2bf(pp);
      }
      rs += __shfl_xor(rs, 1);
      rs += __shfl_xor(rs, 2);
      rs += __shfl_xor(rs, 4);
      rs += __shfl_xor(rs, 8);
      l_i[r] = l_i[r] * alpha + rs;
      m_i[r] = newm;
      alph[r] = alpha;
    }
#pragma unroll
    for (int nt = 0; nt < 4; ++nt)
#pragma unroll
      for (int r = 0; r < 4; ++r) Oacc[nt][r] *= alph[r];
#pragma unroll
    for (int ks = 0; ks < 2; ++ks) {
      s16x8 pa = *(const s16x8*)&Psl[wave][l16 * 72 + quad * 8 + 32 * ks];
#pragma unroll
      for (int nt = 0; nt < 4; ++nt) {
        s16x8 vb = *(const s16x8*)&Vtl[(nt * 16 + l16) * 72 + quad * 8 + 32 * ks];
        Oacc[nt] = MFMA32(pa, vb, Oacc[nt]);
      }
    }
  }
#pragma unroll
  for (int nt = 0; nt < 4; ++nt)
#pragma unroll
    for (int r = 0; r < 4; ++r) {
      int row = q0 + wave * 16 + quad * 4 + r;
      int col = h * 64 + nt * 16 + l16;
      AO[((size_t)b * L_ + row) * E_ + col] = f2bf(Oacc[nt][r] / l_i[r]);
    }
}

// ======================= launch =======================
extern "C" void kernel_launch(void* const* d_in, const int* in_sizes, int n_in,
                              void* d_out, int out_size, void* d_ws, size_t ws_size,
                              hipStream_t stream) {
  const void* queries = d_in[0];
  const void* keys = d_in[1];
  const void* values = d_in[2];
  const int* mask = (const int*)d_in[3];
  const void* Wq = d_in[4];
  const void* Wk = d_in[5];
  const void* Wv = d_in[6];
  const void* Wo = d_in[7];
  const void* bo = d_in[8];

  char* ws = (char*)d_ws;
  const int words = B_ * L_ * (L_ / 64);
  const size_t SZQ = (size_t)B_ * L_ * E_ * 2;  // 16 MiB
  const size_t SZW = (size_t)E_ * E_ * 2;       // 2 MiB
  const size_t NEED1 = 111153408;
  const size_t NEED2 = 113254400 + 8192;

  if (ws_size >= NEED1) {
    u16* qc = (u16*)(ws + 0);
    u16* kc = (u16*)(ws + SZQ);
    u16* vc = (u16*)(ws + 2 * SZQ);
    u16* wqc = (u16*)(ws + 3 * SZQ);
    u16* wkc = (u16*)(ws + 3 * SZQ + SZW);
    u16* wvc = (u16*)(ws + 3 * SZQ + 2 * SZW);
    u16* woc = (u16*)(ws + 3 * SZQ + 3 * SZW);
    float* bo_f = (float*)(ws + 3 * SZQ + 4 * SZW);
    char* p2 = ws + 3 * SZQ + 4 * SZW + 4096;
    u16* Qp = (u16*)(p2);
    u16* Kp = (u16*)(p2 + SZQ);
    u16* VpT = (u16*)(p2 + 2 * SZQ);
    unsigned long long* Mb = (unsigned long long*)(p2 + 3 * SZQ);
    u16* AO = qc;

    if (ws_size >= NEED2) {
      // ---- tier 1: split-K attention ----
      char* st = p2 + 3 * SZQ + (size_t)words * 8;
      float* m0a = (float*)(st);
      float* l0a = (float*)(st + 524288);
      float* m1a = (float*)(st + 2 * 524288);
      float* l1a = (float*)(st + 3 * 524288);
      char* pf = st + 4 * 524288;
      int* flag = (int*)pf;
      unsigned* gflag = (unsigned*)(pf + 8);
      u16* Os0 = kc;  // kc/vc dead after projections
      u16* Os1 = vc;

      hipLaunchKernelGGL(prep_k2, dim3(MBLK + CVB), dim3(256), 0, stream,
                         mask, Mb, gflag,
                         queries, keys, values, Wq, Wk, Wv, Wo, bo,
                         qc, kc, vc, wqc, wkc, wvc, woc, bo_f, flag);
      hipLaunchKernelGGL(gemm_proj_k, dim3(E_ / 128, (B_ * L_) / 128, 3), dim3(256), 0, stream,
                         queries, keys, values, Wq, Wk, Wv,
                         qc, kc, vc, wqc, wkc, wvc, Qp, Kp, VpT, flag);
      hipLaunchKernelGGL(attn_sp, dim3(64, H_, B_), dim3(256), 0, stream,
                         Qp, Kp, VpT, Mb, gflag, Os0, Os1, m0a, l0a, m1a, l1a);
      hipLaunchKernelGGL(merge_k, dim3((B_ * H_ * L_ * D_ / 8) / 256), dim3(256), 0, stream,
                         Os0, Os1, m0a, l0a, m1a, l1a, AO);
      hipLaunchKernelGGL(gemm_out_k, dim3(E_ / 128, (B_ * L_) / 128, 1), dim3(256), 0, stream,
                         AO, Wo, woc, bo_f, d_out, flag);
    } else {
      // ---- tier 2: R6 path ----
      char* pf = p2 + 3 * SZQ + (size_t)words * 8;
      int* flag = (int*)pf;
      unsigned* gflag = (unsigned*)(pf + 8);

      hipLaunchKernelGGL(prep_k2, dim3(MBLK + CVB), dim3(256), 0, stream,
                         mask, Mb, gflag,
                         queries, keys, values, Wq, Wk, Wv, Wo, bo,
                         qc, kc, vc, wqc, wkc, wvc, woc, bo_f, flag);
      hipLaunchKernelGGL(gemm_proj_k, dim3(E_ / 128, (B_ * L_) / 128, 3), dim3(256), 0, stream,
                         queries, keys, values, Wq, Wk, Wv,
                         qc, kc, vc, wqc, wkc, wvc, Qp, Kp, VpT, flag);
      hipLaunchKernelGGL(attn_st3, dim3(L_ / 64, H_, B_), dim3(256), 0, stream,
                         Qp, Kp, VpT, Mb, gflag, AO);
      hipLaunchKernelGGL(gemm_out_k, dim3(E_ / 128, (B_ * L_) / 128, 1), dim3(256), 0, stream,
                         AO, Wo, woc, bo_f, d_out, flag);
    }
  } else {
    // ---- tier 3: legacy ----
    const size_t SEG = (size_t)B_ * H_ * L_ * D_ * sizeof(u16);
    u16* Qp = (u16*)(ws);
    u16* Kp = (u16*)(ws + SEG);
    u16* Vp = (u16*)(ws + 2 * SEG);
    u16* AO = (u16*)(ws + 3 * SEG);
    int* flag = (int*)(ws + 4 * SEG);
    unsigned* gflag = (unsigned*)(ws + 4 * SEG + 8);
    unsigned long long* Mb = (unsigned long long*)(ws + 4 * SEG + 256);

    hipLaunchKernelGGL(detect_k, dim3(1), dim3(256), 0, stream, (const u16*)queries, flag);
    (void)hipMemsetAsync(gflag, 1, 4, stream);
    hipLaunchKernelGGL(mask_bits_k, dim3(words / 4), dim3(256), 0, stream, mask, Mb, gflag, words);
    dim3 g1(E_ / 128, (B_ * L_) / 128, 3);
    hipLaunchKernelGGL((gemm128<1>), g1, dim3(256), 0, stream,
                       queries, keys, values, Wq, Wk, Wv, (const void*)nullptr,
                       (void*)Qp, Kp, Vp, B_ * L_, E_, E_, flag);
    hipLaunchKernelGGL(attn64, dim3(L_ / 64, H_, B_), dim3(256), 0, stream, Qp, Kp, Vp, Mb, AO);
    dim3 g2(E_ / 128, (B_ * L_) / 128, 1);
    hipLaunchKernelGGL((gemm128<0>), g2, dim3(256), 0, stream,
                       (const void*)AO, (const void*)nullptr, (const void*)nullptr,
                       Wo, (const void*)nullptr, (const void*)nullptr, bo,
                       d_out, (u16*)nullptr, (u16*)nullptr, B_ * L_, E_, E_, flag);
  }
}